// Round 1
// baseline (1140.280 us; speedup 1.0000x reference)
//
#include <hip/hip_runtime.h>
#include <math.h>

// ---------------- problem constants ----------------
#define L_SEQ 256            // sequence length (16x16 image positions)
#define BB    4              // batch
#define DD    512            // channels
#define SEQ   (L_SEQ*BB*DD)  // 524288 floats per sequence tensor
#define MROWS (L_SEQ*BB)     // 1024 rows of 512
#define NHEAD 8
#define DSTATE 64
#define XC    136            // NH + 2*D_STATE

__device__ __forceinline__ float gelu_tanh(float x){
    float x3 = x*x*x;
    return 0.5f*x*(1.0f + tanhf(0.7978845608028654f*(x + 0.044715f*x3)));
}

// out[(l*4+b)*512+c] = in[(b*512+c)*256 + l]   (NCHW image -> sequence)
__global__ void to_seq_kernel(const float* __restrict__ in, float* __restrict__ out){
    int idx = blockIdx.x*256 + threadIdx.x;
    int c = idx & 511;
    int b = (idx >> 9) & 3;
    int l = idx >> 11;
    out[idx] = in[(b*512 + c)*256 + l];
}

// d_out[(b*512+c)*256+l] = in[(l*4+b)*512+c]   (sequence -> NCHW image)
__global__ void from_seq_kernel(const float* __restrict__ in, float* __restrict__ out){
    int idx = blockIdx.x*256 + threadIdx.x;
    int l = idx & 255;
    int c = (idx >> 8) & 511;
    int b = idx >> 17;
    out[idx] = in[(l*4 + b)*512 + c];
}

__global__ void add_kernel(const float* __restrict__ a, const float* __restrict__ b,
                           float* __restrict__ o, int n){
    int i = blockIdx.x*256 + threadIdx.x;
    if (i < n) o[i] = a[i] + b[i];
}

// adaptive avg-pool 16x16 -> 18x18, output transposed: pooledT[(b*324+ij)*512 + c]
__global__ void pool_kernel(const float* __restrict__ content, float* __restrict__ pooledT){
    int bij = blockIdx.x;            // 0..1295
    int b = bij / 324;
    int ij = bij % 324;
    int i = ij / 18, j = ij % 18;
    int s0 = (i*16)/18,  e0 = ((i+1)*16 + 17)/18;
    int s1 = (j*16)/18,  e1 = ((j+1)*16 + 17)/18;
    float inv = 1.0f / (float)((e0-s0)*(e1-s1));
    for (int c = threadIdx.x; c < 512; c += 256){
        float acc = 0.f;
        for (int h = s0; h < e0; ++h)
            for (int w = s1; w < e1; ++w)
                acc += content[((b*512 + c)*16 + h)*16 + w];
        pooledT[(size_t)(b*324 + ij)*512 + c] = acc * inv;
    }
}

// jax.image.resize 'linear' antialias: in=18, out=16, scale=16/18, kernel_scale=18/16
__device__ __forceinline__ int resize_taps(int o, float* w, int* j0_out){
    const float inv_scale = 18.0f/16.0f;
    float sf = (o + 0.5f)*inv_scale - 0.5f;
    int j0 = (int)ceilf(sf - inv_scale);
    int j1 = (int)floorf(sf + inv_scale);
    if (j0 < 0) j0 = 0;
    if (j1 > 17) j1 = 17;
    int n = j1 - j0 + 1;
    float sum = 0.f;
    for (int t = 0; t < n; ++t){
        float d = fabsf(sf - (float)(j0 + t)) * (16.0f/18.0f);
        float v = fmaxf(0.f, 1.f - d);
        w[t] = v; sum += v;
    }
    float r = 1.f / sum;
    for (int t = 0; t < n; ++t) w[t] *= r;
    *j0_out = j0;
    return n;
}

// pc18T[(b*324 + jy*18+jx)*512 + c]  ->  pc_seq[((y*16+x)*4 + b)*512 + c]
__global__ void resize_kernel(const float* __restrict__ pc18T, float* __restrict__ pc_seq){
    int bid = blockIdx.x;            // 4*256
    int b = bid >> 8;
    int yx = bid & 255;
    int y = yx >> 4, x = yx & 15;
    float wy[3], wx[3];
    int jy0, jx0;
    int ny = resize_taps(y, wy, &jy0);
    int nx = resize_taps(x, wx, &jx0);
    for (int c = threadIdx.x; c < 512; c += 256){
        float acc = 0.f;
        for (int ty = 0; ty < ny; ++ty)
            for (int tx = 0; tx < nx; ++tx)
                acc += wy[ty]*wx[tx] *
                       pc18T[(size_t)(b*324 + (jy0+ty)*18 + (jx0+tx))*512 + c];
        pc_seq[(size_t)((y*16 + x)*4 + b)*512 + c] = acc;
    }
}

// LayerNorm over last dim (512). One wave (64 lanes) per row, 4 rows/block.
// out[row] = LN(in0[row] (+ in1[row])) * w + b ; accumulate ? out += : out =
__global__ __launch_bounds__(256) void ln_kernel(
    const float* __restrict__ in0, const float* __restrict__ in1,
    const float* __restrict__ w, const float* __restrict__ b,
    float* __restrict__ out, int M, int accumulate)
{
    int wave = threadIdx.x >> 6;
    int lane = threadIdx.x & 63;
    int row = blockIdx.x*4 + wave;
    if (row >= M) return;
    const float* p0 = in0 + (size_t)row*512;
    const float* p1 = in1 ? in1 + (size_t)row*512 : nullptr;
    int base = lane*8;
    float v[8];
    #pragma unroll
    for (int t = 0; t < 8; ++t){
        v[t] = p0[base + t];
        if (p1) v[t] += p1[base + t];
    }
    float s = 0.f;
    #pragma unroll
    for (int t = 0; t < 8; ++t) s += v[t];
    #pragma unroll
    for (int off = 32; off > 0; off >>= 1) s += __shfl_xor(s, off, 64);
    float mean = s * (1.f/512.f);
    float sq = 0.f;
    #pragma unroll
    for (int t = 0; t < 8; ++t){ float d = v[t] - mean; sq += d*d; }
    #pragma unroll
    for (int off = 32; off > 0; off >>= 1) sq += __shfl_xor(sq, off, 64);
    float rstd = rsqrtf(sq * (1.f/512.f) + 1e-5f);
    #pragma unroll
    for (int t = 0; t < 8; ++t){
        float o = (v[t] - mean)*rstd*w[base + t] + b[base + t];
        size_t oi = (size_t)row*512 + base + t;
        if (accumulate) out[oi] += o; else out[oi] = o;
    }
}

// depthwise conv: only kw=1 column matters since W=1. + bias + gelu.
// also writes reversed-along-l copy.
__global__ void conv_gelu_kernel(const float* __restrict__ u,
    const float* __restrict__ cw, const float* __restrict__ cb,
    float* __restrict__ v, float* __restrict__ vrev)
{
    int idx = blockIdx.x*256 + threadIdx.x;   // SEQ
    int d = idx & 511;
    int l = (idx >> 9) & 3;
    int bt = idx >> 11;
    float acc = cb[d];
    #pragma unroll
    for (int kh = 0; kh < 3; ++kh){
        int hh = l + kh - 1;
        if (hh >= 0 && hh < 4)
            acc += u[(size_t)(bt*4 + hh)*512 + d] * cw[(d*3 + kh)*3 + 1];
    }
    float g = gelu_tanh(acc);
    v[idx] = g;
    vrev[(size_t)(bt*4 + (3 - l))*512 + d] = g;
}

// generic fp32 GEMM: C[M,N] = A[M,K] * W[N,K]^T (+bias) (+gelu) (+residual)
__global__ __launch_bounds__(256) void gemm_kernel(
    const float* __restrict__ A, const float* __restrict__ W,
    const float* __restrict__ bias, const float* __restrict__ res,
    float* __restrict__ C, int M, int N, int K, int act)
{
    __shared__ float As[16][68];
    __shared__ float Ws[16][68];
    const int bn = blockIdx.x * 64;
    const int bm = blockIdx.y * 64;
    const int tid = threadIdx.x;
    const int tx = tid & 15, ty = tid >> 4;
    const int lr = tid >> 2;          // 0..63  staged row
    const int lk = (tid & 3) * 4;     // 0,4,8,12 k offset
    float acc[4][4] = {};
    for (int k0 = 0; k0 < K; k0 += 16){
        float4 av = make_float4(0,0,0,0), wv = make_float4(0,0,0,0);
        int am = bm + lr;
        if (am < M) av = *(const float4*)(A + (size_t)am*K + k0 + lk);
        int wn = bn + lr;
        if (wn < N) wv = *(const float4*)(W + (size_t)wn*K + k0 + lk);
        __syncthreads();
        As[lk+0][lr] = av.x; As[lk+1][lr] = av.y; As[lk+2][lr] = av.z; As[lk+3][lr] = av.w;
        Ws[lk+0][lr] = wv.x; Ws[lk+1][lr] = wv.y; Ws[lk+2][lr] = wv.z; Ws[lk+3][lr] = wv.w;
        __syncthreads();
        #pragma unroll
        for (int kk = 0; kk < 16; ++kk){
            float4 a4 = *(const float4*)&As[kk][ty*4];
            float4 w4 = *(const float4*)&Ws[kk][tx*4];
            float as[4] = {a4.x, a4.y, a4.z, a4.w};
            float wsv[4] = {w4.x, w4.y, w4.z, w4.w};
            #pragma unroll
            for (int i2 = 0; i2 < 4; ++i2)
                #pragma unroll
                for (int j2 = 0; j2 < 4; ++j2)
                    acc[i2][j2] += as[i2]*wsv[j2];
        }
    }
    #pragma unroll
    for (int i2 = 0; i2 < 4; ++i2){
        int m = bm + ty*4 + i2;
        if (m >= M) continue;
        #pragma unroll
        for (int j2 = 0; j2 < 4; ++j2){
            int n = bn + tx*4 + j2;
            if (n >= N) continue;
            float v = acc[i2][j2];
            if (bias) v += bias[n];
            if (act == 1) v = gelu_tanh(v);
            if (res) v += res[(size_t)m*N + n];
            C[(size_t)m*N + n] = v;
        }
    }
}

// selective scan: 64 lanes per (bt,k,nh) head; lane owns output dim d,
// holds h[d][n=0..63] in registers. L=4 steps.
__global__ __launch_bounds__(256) void scan_kernel(
    const float* __restrict__ xdbl,   // [4][1024][136]  (k-major)
    const float* __restrict__ v,      // [1024][512]
    const float* __restrict__ vrev,   // [1024][512]
    const float* __restrict__ dt_bias,// [4][8]  (already offset by i)
    const float* __restrict__ A_log,  // [4][8]
    const float* __restrict__ Dp,     // [4][8]
    float* __restrict__ ys)           // [256][4][4][512]
{
    __shared__ float Bs[4][64];
    __shared__ float Cs[4][64];
    int grp  = threadIdx.x >> 6;
    int lane = threadIdx.x & 63;
    int gid = blockIdx.x*4 + grp;     // 0..8191
    int bt = gid >> 5;
    int k  = (gid >> 3) & 3;
    int nh = gid & 7;
    float A  = -expf(A_log[k*8 + nh]);
    float Dv = Dp[k*8 + nh];
    float dtb = dt_bias[k*8 + nh];
    const float* xsrc = (k < 2) ? v : vrev;
    float h[64];
    #pragma unroll
    for (int n = 0; n < 64; ++n) h[n] = 0.f;
    for (int l = 0; l < 4; ++l){
        const float* row = xdbl + (size_t)((k*1024 + bt*4 + l))*136;
        float draw = row[nh] + dtb;
        float dt = fmaxf(draw, 0.f) + log1pf(expf(-fabsf(draw)));   // softplus
        float dA = expf(dt * A);
        __syncthreads();
        Bs[grp][lane] = row[8 + lane];
        Cs[grp][lane] = row[72 + lane];
        __syncthreads();
        float xd = xsrc[(size_t)(bt*4 + l)*512 + nh*64 + lane];
        float dtx = dt * xd;
        float y = 0.f;
        #pragma unroll
        for (int n = 0; n < 64; ++n){
            h[n] = h[n]*dA + dtx*Bs[grp][n];
            y += h[n]*Cs[grp][n];
        }
        ys[(size_t)((bt*4 + k)*4 + l)*512 + nh*64 + lane] = y + Dv*xd;
    }
}

// y[bt,l,:] = ys[bt,0,l] + ys[bt,1,l] + ys[bt,2,3-l] + ys[bt,3,3-l]
__global__ void combine_kernel(const float* __restrict__ ys, float* __restrict__ y){
    int idx = blockIdx.x*256 + threadIdx.x;  // SEQ
    int d = idx & 511;
    int l = (idx >> 9) & 3;
    int bt = idx >> 11;
    int rl = 3 - l;
    y[idx] = ys[(size_t)((bt*4+0)*4 + l )*512 + d]
           + ys[(size_t)((bt*4+1)*4 + l )*512 + d]
           + ys[(size_t)((bt*4+2)*4 + rl)*512 + d]
           + ys[(size_t)((bt*4+3)*4 + rl)*512 + d];
}

extern "C" void kernel_launch(void* const* d_in, const int* in_sizes, int n_in,
                              void* d_out, int out_size, void* d_ws, size_t ws_size,
                              hipStream_t stream)
{
    const float* style   = (const float*)d_in[0];
    const float* content = (const float*)d_in[2];
    const float* pos_s   = (const float*)d_in[4];
    const float* newps_w = (const float*)d_in[5];
    const float* newps_b = (const float*)d_in[6];
    const float* vln_w   = (const float*)d_in[7];
    const float* vln_b   = (const float*)d_in[8];
    const float* vin_w   = (const float*)d_in[9];
    const float* vin_b   = (const float*)d_in[10];
    const float* vconv_w = (const float*)d_in[11];
    const float* vconv_b = (const float*)d_in[12];
    const float* vxproj_w= (const float*)d_in[13];
    const float* vdt_bias= (const float*)d_in[14];
    const float* vA_log  = (const float*)d_in[15];
    const float* vD      = (const float*)d_in[16];
    const float* von_w   = (const float*)d_in[17];
    const float* von_b   = (const float*)d_in[18];
    const float* vout_w  = (const float*)d_in[19];
    const float* vout_b  = (const float*)d_in[20];
    const float* lin1_w  = (const float*)d_in[21];
    const float* lin1_b  = (const float*)d_in[22];
    const float* lin2_w  = (const float*)d_in[23];
    const float* lin2_b  = (const float*)d_in[24];
    const float* dn1_w   = (const float*)d_in[25];
    const float* dn1_b   = (const float*)d_in[26];
    const float* dn2_w   = (const float*)d_in[27];
    const float* dn2_b   = (const float*)d_in[28];
    const float* dn3_w   = (const float*)d_in[29];
    const float* dn3_b   = (const float*)d_in[30];
    const float* decn_w  = (const float*)d_in[31];
    const float* decn_b  = (const float*)d_in[32];

    float* out = (float*)d_out;
    float* ws  = (float*)d_ws;

    // ---- workspace layout (units of SEQ floats; total 22*SEQ = 44 MB) ----
    float* s_seq   = ws + (size_t) 0*SEQ;
    float* c_seq   = ws + (size_t) 1*SEQ;
    float* ps_seq  = ws + (size_t) 2*SEQ;
    float* pc_seq  = ws + (size_t) 3*SEQ;
    float* s_enc   = ws + (size_t) 4*SEQ;
    float* c_enc   = ws + (size_t) 5*SEQ;
    float* qbuf    = ws + (size_t) 6*SEQ;
    float* kbuf    = ws + (size_t) 7*SEQ;
    float* t1      = ws + (size_t) 8*SEQ;
    float* t2      = ws + (size_t) 9*SEQ;
    float* tgt     = ws + (size_t)10*SEQ;
    float* ffnout  = ws + (size_t)11*SEQ;
    float* xn      = ws + (size_t)12*SEQ;   // vss scratch; also yln, tgt2
    float* ubuf    = ws + (size_t)13*SEQ;   // vss scratch; also ybuf, tgt3
    float* vbuf    = ws + (size_t)14*SEQ;
    float* vrev    = ws + (size_t)15*SEQ;
    float* xdbl    = ws + (size_t)16*SEQ;   // 4*1024*136 = 557056 (< 2*SEQ)
    float* ysbuf   = ws + (size_t)18*SEQ;   // 4*SEQ
    float* pooledT = ws + (size_t)16*SEQ;   // pre-VSS only (663552)
    float* pc18T   = ws + (size_t)18*SEQ;   // pre-VSS only (663552)
    float* ffn_mid = ws + (size_t)18*SEQ;   // post-VSS only (4*SEQ)
    float* yln     = xn;
    float* ybuf    = ubuf;
    float* tgt2    = xn;
    float* tgt3    = ubuf;

    auto gemm = [&](const float* A, const float* W, const float* bias,
                    const float* res, float* C, int M, int N, int K, int act){
        dim3 g((N + 63)/64, (M + 63)/64);
        gemm_kernel<<<g, 256, 0, stream>>>(A, W, bias, res, C, M, N, K, act);
    };

    auto vss = [&](const float* x, int i, float* o){
        ln_kernel<<<256, 256, 0, stream>>>(x, nullptr, vln_w + i*512, vln_b + i*512,
                                           xn, MROWS, 0);
        gemm(xn, vin_w + (size_t)i*512*512, vin_b + i*512, nullptr, ubuf,
             MROWS, 512, 512, 0);
        conv_gelu_kernel<<<SEQ/256, 256, 0, stream>>>(ubuf, vconv_w + (size_t)i*512*9,
                                                      vconv_b + i*512, vbuf, vrev);
        for (int k = 0; k < 4; ++k){
            gemm(k < 2 ? vbuf : vrev,
                 vxproj_w + (size_t)(i*4 + k)*136*512, nullptr, nullptr,
                 xdbl + (size_t)k*1024*136, MROWS, 136, 512, 0);
        }
        scan_kernel<<<2048, 256, 0, stream>>>(xdbl, vbuf, vrev,
                                              vdt_bias + i*32, vA_log + i*32, vD + i*32,
                                              ysbuf);
        combine_kernel<<<SEQ/256, 256, 0, stream>>>(ysbuf, ybuf);
        ln_kernel<<<256, 256, 0, stream>>>(ybuf, nullptr, von_w + i*512, von_b + i*512,
                                           yln, MROWS, 0);
        gemm(yln, vout_w + (size_t)i*512*512, vout_b + i*512, x, o,
             MROWS, 512, 512, 0);
    };

    // ---- positional embedding path ----
    to_seq_kernel<<<SEQ/256, 256, 0, stream>>>(style,   s_seq);
    to_seq_kernel<<<SEQ/256, 256, 0, stream>>>(content, c_seq);
    to_seq_kernel<<<SEQ/256, 256, 0, stream>>>(pos_s,   ps_seq);
    pool_kernel<<<4*324, 256, 0, stream>>>(content, pooledT);
    gemm(pooledT, newps_w, newps_b, nullptr, pc18T, 4*324, 512, 512, 0);
    resize_kernel<<<4*256, 256, 0, stream>>>(pc18T, pc_seq);

    // ---- encoders ----
    vss(s_seq, 0, s_enc);
    vss(c_seq, 1, c_enc);
    add_kernel<<<SEQ/256, 256, 0, stream>>>(c_enc, pc_seq, qbuf, SEQ);
    add_kernel<<<SEQ/256, 256, 0, stream>>>(s_enc, ps_seq, kbuf, SEQ);

    // ---- decoder ----
    vss(qbuf, 2, t1);
    ln_kernel<<<256, 256, 0, stream>>>(c_enc, t1, dn1_w, dn1_b, tgt, MROWS, 0);
    vss(kbuf, 3, t2);
    ln_kernel<<<256, 256, 0, stream>>>(s_enc, t2, dn2_w, dn2_b, tgt, MROWS, 1);

    gemm(tgt, lin1_w, lin1_b, nullptr, ffn_mid, MROWS, 2048, 512, 1);
    gemm(ffn_mid, lin2_w, lin2_b, nullptr, ffnout, MROWS, 512, 2048, 0);
    ln_kernel<<<256, 256, 0, stream>>>(tgt, ffnout, dn3_w, dn3_b, tgt2, MROWS, 0);
    ln_kernel<<<256, 256, 0, stream>>>(tgt2, nullptr, decn_w, decn_b, tgt3, MROWS, 0);

    from_seq_kernel<<<SEQ/256, 256, 0, stream>>>(tgt3, out);
}

// Round 2
// 473.534 us; speedup vs baseline: 2.4080x; 2.4080x over previous
//
#include <hip/hip_runtime.h>
#include <hip/hip_bf16.h>
#include <math.h>

// ---------------- problem constants ----------------
#define L_SEQ 256            // sequence length (16x16 image positions)
#define BB    4              // batch (acts as H inside VSS)
#define DD    512
#define SEQ   (L_SEQ*BB*DD)  // 524288 floats per sequence tensor
#define MROWS (L_SEQ*BB)     // 1024 rows of 512
#define NHEAD 8
#define DSTATE 64
#define XC    136            // NH + 2*D_STATE

typedef __bf16 bf8 __attribute__((ext_vector_type(8)));
typedef float f32x4 __attribute__((ext_vector_type(4)));

__device__ __forceinline__ float gelu_tanh(float x){
    float x3 = x*x*x;
    return 0.5f*x*(1.0f + tanhf(0.7978845608028654f*(x + 0.044715f*x3)));
}

__device__ __forceinline__ unsigned short bfbits(float x){
    union { __hip_bfloat16 h; unsigned short u; } cv;
    cv.h = __float2bfloat16(x);
    return cv.u;
}

// style/content/pos_s -> sequence layout, one launch. idx>>19 picks tensor.
__global__ void to_seq3_kernel(const float* __restrict__ s, const float* __restrict__ c,
                               const float* __restrict__ p,
                               float* __restrict__ os, float* __restrict__ oc,
                               float* __restrict__ op){
    int idx = blockIdx.x*256 + threadIdx.x;
    int which = idx >> 19;
    int i = idx & (SEQ-1);
    const float* in = which==0 ? s : (which==1 ? c : p);
    float* o = which==0 ? os : (which==1 ? oc : op);
    int cc = i & 511;
    int b = (i >> 9) & 3;
    int l = i >> 11;
    o[i] = in[(b*512 + cc)*256 + l];
}

// d_out[(b*512+c)*256+l] = in[(l*4+b)*512+c]
__global__ void from_seq_kernel(const float* __restrict__ in, float* __restrict__ out){
    int idx = blockIdx.x*256 + threadIdx.x;
    int l = idx & 255;
    int c = (idx >> 8) & 511;
    int b = idx >> 17;
    out[idx] = in[(l*4 + b)*512 + c];
}

// adaptive avg-pool 16x16 -> 18x18, transposed out: pooledT[(b*324+ij)*512 + c]
__global__ void pool_kernel(const float* __restrict__ content, float* __restrict__ pooledT){
    int bij = blockIdx.x;
    int b = bij / 324;
    int ij = bij % 324;
    int i = ij / 18, j = ij % 18;
    int s0 = (i*16)/18,  e0 = ((i+1)*16 + 17)/18;
    int s1 = (j*16)/18,  e1 = ((j+1)*16 + 17)/18;
    float inv = 1.0f / (float)((e0-s0)*(e1-s1));
    for (int c = threadIdx.x; c < 512; c += 256){
        float acc = 0.f;
        for (int h = s0; h < e0; ++h)
            for (int w = s1; w < e1; ++w)
                acc += content[((b*512 + c)*16 + h)*16 + w];
        pooledT[(size_t)(b*324 + ij)*512 + c] = acc * inv;
    }
}

__device__ __forceinline__ int resize_taps(int o, float* w, int* j0_out){
    const float inv_scale = 18.0f/16.0f;
    float sf = (o + 0.5f)*inv_scale - 0.5f;
    int j0 = (int)ceilf(sf - inv_scale);
    int j1 = (int)floorf(sf + inv_scale);
    if (j0 < 0) j0 = 0;
    if (j1 > 17) j1 = 17;
    int n = j1 - j0 + 1;
    float sum = 0.f;
    for (int t = 0; t < n; ++t){
        float d = fabsf(sf - (float)(j0 + t)) * (16.0f/18.0f);
        float v = fmaxf(0.f, 1.f - d);
        w[t] = v; sum += v;
    }
    float r = 1.f / sum;
    for (int t = 0; t < n; ++t) w[t] *= r;
    *j0_out = j0;
    return n;
}

__global__ void resize_kernel(const float* __restrict__ pc18T, float* __restrict__ pc_seq){
    int bid = blockIdx.x;            // 4*256
    int b = bid >> 8;
    int yx = bid & 255;
    int y = yx >> 4, x = yx & 15;
    float wy[3], wx[3];
    int jy0, jx0;
    int ny = resize_taps(y, wy, &jy0);
    int nx = resize_taps(x, wx, &jx0);
    for (int c = threadIdx.x; c < 512; c += 256){
        float acc = 0.f;
        for (int ty = 0; ty < ny; ++ty)
            for (int tx = 0; tx < nx; ++tx)
                acc += wy[ty]*wx[tx] *
                       pc18T[(size_t)(b*324 + (jy0+ty)*18 + (jx0+tx))*512 + c];
        pc_seq[(size_t)((y*16 + x)*4 + b)*512 + c] = acc;
    }
}

// LayerNorm over 512. One wave per row, 4 rows/block. optional in1 add, accumulate.
__global__ __launch_bounds__(256) void ln_kernel(
    const float* __restrict__ in0, const float* __restrict__ in1,
    const float* __restrict__ w, const float* __restrict__ b,
    float* __restrict__ out, int M, int accumulate)
{
    int wave = threadIdx.x >> 6;
    int lane = threadIdx.x & 63;
    int row = blockIdx.x*4 + wave;
    if (row >= M) return;
    const float* p0 = in0 + (size_t)row*512;
    const float* p1 = in1 ? in1 + (size_t)row*512 : nullptr;
    int base = lane*8;
    float v[8];
    #pragma unroll
    for (int t = 0; t < 8; ++t){
        v[t] = p0[base + t];
        if (p1) v[t] += p1[base + t];
    }
    float s = 0.f;
    #pragma unroll
    for (int t = 0; t < 8; ++t) s += v[t];
    #pragma unroll
    for (int off = 32; off > 0; off >>= 1) s += __shfl_xor(s, off, 64);
    float mean = s * (1.f/512.f);
    float sq = 0.f;
    #pragma unroll
    for (int t = 0; t < 8; ++t){ float d = v[t] - mean; sq += d*d; }
    #pragma unroll
    for (int off = 32; off > 0; off >>= 1) sq += __shfl_xor(sq, off, 64);
    float rstd = rsqrtf(sq * (1.f/512.f) + 1e-5f);
    #pragma unroll
    for (int t = 0; t < 8; ++t){
        float o = (v[t] - mean)*rstd*w[base + t] + b[base + t];
        size_t oi = (size_t)row*512 + base + t;
        if (accumulate) out[oi] += o; else out[oi] = o;
    }
}

// double-LN: y = LN(LN(in0+in1; w1,b1); w2,b2)
__global__ __launch_bounds__(256) void ln2_kernel(
    const float* __restrict__ in0, const float* __restrict__ in1,
    const float* __restrict__ w1, const float* __restrict__ b1,
    const float* __restrict__ w2, const float* __restrict__ b2,
    float* __restrict__ out)
{
    int wave = threadIdx.x >> 6;
    int lane = threadIdx.x & 63;
    int row = blockIdx.x*4 + wave;
    const float* p0 = in0 + (size_t)row*512;
    const float* p1 = in1 + (size_t)row*512;
    int base = lane*8;
    float v[8];
    #pragma unroll
    for (int t = 0; t < 8; ++t) v[t] = p0[base + t] + p1[base + t];
    float s = 0.f;
    #pragma unroll
    for (int t = 0; t < 8; ++t) s += v[t];
    #pragma unroll
    for (int off = 32; off > 0; off >>= 1) s += __shfl_xor(s, off, 64);
    float mean = s * (1.f/512.f);
    float sq = 0.f;
    #pragma unroll
    for (int t = 0; t < 8; ++t){ float d = v[t] - mean; sq += d*d; }
    #pragma unroll
    for (int off = 32; off > 0; off >>= 1) sq += __shfl_xor(sq, off, 64);
    float rstd = rsqrtf(sq * (1.f/512.f) + 1e-5f);
    #pragma unroll
    for (int t = 0; t < 8; ++t) v[t] = (v[t] - mean)*rstd*w1[base + t] + b1[base + t];
    // second LN
    s = 0.f;
    #pragma unroll
    for (int t = 0; t < 8; ++t) s += v[t];
    #pragma unroll
    for (int off = 32; off > 0; off >>= 1) s += __shfl_xor(s, off, 64);
    mean = s * (1.f/512.f);
    sq = 0.f;
    #pragma unroll
    for (int t = 0; t < 8; ++t){ float d = v[t] - mean; sq += d*d; }
    #pragma unroll
    for (int off = 32; off > 0; off >>= 1) sq += __shfl_xor(sq, off, 64);
    rstd = rsqrtf(sq * (1.f/512.f) + 1e-5f);
    #pragma unroll
    for (int t = 0; t < 8; ++t)
        out[(size_t)row*512 + base + t] = (v[t] - mean)*rstd*w2[base + t] + b2[base + t];
}

// depthwise conv (kw=1 col only since W=1) + bias + gelu; writes fwd and l-reversed.
__global__ void conv_gelu_kernel(const float* __restrict__ u,
    const float* __restrict__ cw, const float* __restrict__ cb,
    float* __restrict__ v, float* __restrict__ vrev)
{
    int idx = blockIdx.x*256 + threadIdx.x;   // SEQ
    int d = idx & 511;
    int l = (idx >> 9) & 3;
    int bt = idx >> 11;
    float acc = cb[d];
    #pragma unroll
    for (int kh = 0; kh < 3; ++kh){
        int hh = l + kh - 1;
        if (hh >= 0 && hh < 4)
            acc += u[(size_t)(bt*4 + hh)*512 + d] * cw[(d*3 + kh)*3 + 1];
    }
    float g = gelu_tanh(acc);
    v[idx] = g;
    vrev[(size_t)(bt*4 + (3 - l))*512 + d] = g;
}

// ---------------- bf16 MFMA GEMM ----------------
// C[M,N] = A[M,K] * W[N,K]^T (+bias)(+gelu)(+res1+res2)
// mode==1 (xproj): gridDim.z==2, z picks A (fwd) vs A2 (rev) and W += z*272*K;
//   epilogue scatters to xdbl[((z*2 + n/136)*1024 + m)*136 + n%136], N==272.
// 64x64 tile, 4 waves (2x2), each wave 32x32 via 2x2 mfma_f32_16x16x32_bf16.
// LDS: A/W tiles 64x32 bf16, 16B-slot XOR swizzle (slot = kq ^ (row&3)).
__global__ __launch_bounds__(256) void gemm_bf16_kernel(
    const float* __restrict__ A, const float* __restrict__ A2,
    const float* __restrict__ Wt, const float* __restrict__ bias,
    const float* __restrict__ res1, const float* __restrict__ res2,
    float* __restrict__ C, int M, int N, int K, int act, int mode)
{
    __shared__ __align__(16) char smem[8192];
    char* ldsA = smem;
    char* ldsB = smem + 4096;

    const int z = blockIdx.z;
    const float* Ap = A;
    const float* Wp = Wt;
    if (mode == 1){ if (z) Ap = A2; Wp = Wt + (size_t)z*272*K; }

    const int bm = blockIdx.y*64, bn = blockIdx.x*64;
    const int tid = threadIdx.x;

    // staging: thread -> (row 0..63, kq 0..3), 8 bf16 (16B) per thread per tile
    const int srow = tid >> 2, skq = tid & 3;
    const int sbyte = srow*64 + (((skq ^ srow) & 3) << 4);
    const int gmA = bm + srow;
    const int gnW = bn + srow;
    const bool aOk = gmA < M;
    const bool wOk = gnW < N;
    const float* aSrc = Ap + (size_t)gmA*K + skq*8;
    const float* wSrc = Wp + (size_t)gnW*K + skq*8;

    // fragment read offsets
    const int lane = tid & 63, wave = tid >> 6;
    const int wr = wave >> 1, wc = wave & 1;
    const int frow = lane & 15, fkq = lane >> 4;
    const int fslot = ((fkq ^ frow) & 3) << 4;
    const int aoff0 = (wr*32 + frow)*64 + fslot;
    const int boff0 = (wc*32 + frow)*64 + fslot;

    f32x4 zero4 = {0.f, 0.f, 0.f, 0.f};
    f32x4 acc00 = zero4, acc01 = zero4, acc10 = zero4, acc11 = zero4;

    float4 ra0, ra1, rw0, rw1;
    float4 z4 = make_float4(0,0,0,0);
    ra0 = ra1 = rw0 = rw1 = z4;
    if (aOk){ ra0 = *(const float4*)(aSrc); ra1 = *(const float4*)(aSrc + 4); }
    if (wOk){ rw0 = *(const float4*)(wSrc); rw1 = *(const float4*)(wSrc + 4); }

    for (int k0 = 0; k0 < K; k0 += 32){
        uint4 pa, pw;
        pa.x = bfbits(ra0.x) | ((unsigned)bfbits(ra0.y) << 16);
        pa.y = bfbits(ra0.z) | ((unsigned)bfbits(ra0.w) << 16);
        pa.z = bfbits(ra1.x) | ((unsigned)bfbits(ra1.y) << 16);
        pa.w = bfbits(ra1.z) | ((unsigned)bfbits(ra1.w) << 16);
        pw.x = bfbits(rw0.x) | ((unsigned)bfbits(rw0.y) << 16);
        pw.y = bfbits(rw0.z) | ((unsigned)bfbits(rw0.w) << 16);
        pw.z = bfbits(rw1.x) | ((unsigned)bfbits(rw1.y) << 16);
        pw.w = bfbits(rw1.z) | ((unsigned)bfbits(rw1.w) << 16);
        __syncthreads();
        *(uint4*)(ldsA + sbyte) = pa;
        *(uint4*)(ldsB + sbyte) = pw;
        __syncthreads();
        if (k0 + 32 < K){   // prefetch next k-step; latency hides under MFMA
            ra0 = ra1 = rw0 = rw1 = z4;
            if (aOk){ ra0 = *(const float4*)(aSrc + k0+32); ra1 = *(const float4*)(aSrc + k0+36); }
            if (wOk){ rw0 = *(const float4*)(wSrc + k0+32); rw1 = *(const float4*)(wSrc + k0+36); }
        }
        bf8 a0 = *(const bf8*)(ldsA + aoff0);
        bf8 a1 = *(const bf8*)(ldsA + aoff0 + 16*64);
        bf8 b0 = *(const bf8*)(ldsB + boff0);
        bf8 b1 = *(const bf8*)(ldsB + boff0 + 16*64);
        acc00 = __builtin_amdgcn_mfma_f32_16x16x32_bf16(a0, b0, acc00, 0, 0, 0);
        acc01 = __builtin_amdgcn_mfma_f32_16x16x32_bf16(a0, b1, acc01, 0, 0, 0);
        acc10 = __builtin_amdgcn_mfma_f32_16x16x32_bf16(a1, b0, acc10, 0, 0, 0);
        acc11 = __builtin_amdgcn_mfma_f32_16x16x32_bf16(a1, b1, acc11, 0, 0, 0);
    }

    // epilogue: C/D layout col=lane&15, row=(lane>>4)*4+reg
    const int erow = (lane >> 4) * 4;
    const int ecol = lane & 15;
    f32x4 accs[2][2] = {{acc00, acc01}, {acc10, acc11}};
    #pragma unroll
    for (int i = 0; i < 2; ++i){
        #pragma unroll
        for (int j = 0; j < 2; ++j){
            #pragma unroll
            for (int r = 0; r < 4; ++r){
                int m = bm + wr*32 + i*16 + erow + r;
                int n = bn + wc*32 + j*16 + ecol;
                if (m >= M || n >= N) continue;
                float v = accs[i][j][r];
                if (bias) v += bias[n];
                if (act == 1) v = gelu_tanh(v);
                if (res1) v += res1[(size_t)m*N + n];
                if (res2) v += res2[(size_t)m*N + n];
                if (mode == 1){
                    int kk = (n >= 136) ? 1 : 0;
                    int cc = n - kk*136;
                    C[((size_t)((z*2 + kk)*1024 + m))*136 + cc] = v;
                } else {
                    C[(size_t)m*N + n] = v;
                }
            }
        }
    }
}

// selective scan: 64 lanes per (bt,k,nh) head; L=4 steps, h[64] in regs.
__global__ __launch_bounds__(256) void scan_kernel(
    const float* __restrict__ xdbl,   // [4][1024][136]
    const float* __restrict__ v,      // [1024][512]
    const float* __restrict__ vrev,   // [1024][512]
    const float* __restrict__ dt_bias,
    const float* __restrict__ A_log,
    const float* __restrict__ Dp,
    float* __restrict__ ys)           // [256][4][4][512]
{
    __shared__ float Bs[4][64];
    __shared__ float Cs[4][64];
    int grp  = threadIdx.x >> 6;
    int lane = threadIdx.x & 63;
    int gid = blockIdx.x*4 + grp;
    int bt = gid >> 5;
    int k  = (gid >> 3) & 3;
    int nh = gid & 7;
    float A  = -expf(A_log[k*8 + nh]);
    float Dv = Dp[k*8 + nh];
    float dtb = dt_bias[k*8 + nh];
    const float* xsrc = (k < 2) ? v : vrev;
    float h[64];
    #pragma unroll
    for (int n = 0; n < 64; ++n) h[n] = 0.f;
    for (int l = 0; l < 4; ++l){
        const float* row = xdbl + (size_t)((k*1024 + bt*4 + l))*136;
        float draw = row[nh] + dtb;
        float dt = fmaxf(draw, 0.f) + log1pf(expf(-fabsf(draw)));
        float dA = expf(dt * A);
        __syncthreads();
        Bs[grp][lane] = row[8 + lane];
        Cs[grp][lane] = row[72 + lane];
        __syncthreads();
        float xd = xsrc[(size_t)(bt*4 + l)*512 + nh*64 + lane];
        float dtx = dt * xd;
        float y = 0.f;
        #pragma unroll
        for (int n = 0; n < 64; ++n){
            h[n] = h[n]*dA + dtx*Bs[grp][n];
            y += h[n]*Cs[grp][n];
        }
        ys[(size_t)((bt*4 + k)*4 + l)*512 + nh*64 + lane] = y + Dv*xd;
    }
}

// fused: y = ys[...,0,l] + ys[...,1,l] + ys[...,2,3-l] + ys[...,3,3-l]; out = LN(y)*w+b
__global__ __launch_bounds__(256) void combine_ln_kernel(
    const float* __restrict__ ys, const float* __restrict__ w,
    const float* __restrict__ b, float* __restrict__ out)
{
    int wave = threadIdx.x >> 6;
    int lane = threadIdx.x & 63;
    int row = blockIdx.x*4 + wave;     // bt*4 + l
    int bt = row >> 2, l = row & 3, rl = 3 - l;
    int base = lane*8;
    const float* y0 = ys + ((size_t)(bt*16 + 0 + l ))*512 + base;
    const float* y1 = ys + ((size_t)(bt*16 + 4 + l ))*512 + base;
    const float* y2 = ys + ((size_t)(bt*16 + 8 + rl))*512 + base;
    const float* y3 = ys + ((size_t)(bt*16 + 12 + rl))*512 + base;
    float v[8];
    #pragma unroll
    for (int t = 0; t < 8; ++t) v[t] = y0[t] + y1[t] + y2[t] + y3[t];
    float s = 0.f;
    #pragma unroll
    for (int t = 0; t < 8; ++t) s += v[t];
    #pragma unroll
    for (int off = 32; off > 0; off >>= 1) s += __shfl_xor(s, off, 64);
    float mean = s * (1.f/512.f);
    float sq = 0.f;
    #pragma unroll
    for (int t = 0; t < 8; ++t){ float d = v[t] - mean; sq += d*d; }
    #pragma unroll
    for (int off = 32; off > 0; off >>= 1) sq += __shfl_xor(sq, off, 64);
    float rstd = rsqrtf(sq * (1.f/512.f) + 1e-5f);
    #pragma unroll
    for (int t = 0; t < 8; ++t)
        out[(size_t)row*512 + base + t] = (v[t] - mean)*rstd*w[base + t] + b[base + t];
}

extern "C" void kernel_launch(void* const* d_in, const int* in_sizes, int n_in,
                              void* d_out, int out_size, void* d_ws, size_t ws_size,
                              hipStream_t stream)
{
    const float* style   = (const float*)d_in[0];
    const float* content = (const float*)d_in[2];
    const float* pos_s   = (const float*)d_in[4];
    const float* newps_w = (const float*)d_in[5];
    const float* newps_b = (const float*)d_in[6];
    const float* vln_w   = (const float*)d_in[7];
    const float* vln_b   = (const float*)d_in[8];
    const float* vin_w   = (const float*)d_in[9];
    const float* vin_b   = (const float*)d_in[10];
    const float* vconv_w = (const float*)d_in[11];
    const float* vconv_b = (const float*)d_in[12];
    const float* vxproj_w= (const float*)d_in[13];
    const float* vdt_bias= (const float*)d_in[14];
    const float* vA_log  = (const float*)d_in[15];
    const float* vD      = (const float*)d_in[16];
    const float* von_w   = (const float*)d_in[17];
    const float* von_b   = (const float*)d_in[18];
    const float* vout_w  = (const float*)d_in[19];
    const float* vout_b  = (const float*)d_in[20];
    const float* lin1_w  = (const float*)d_in[21];
    const float* lin1_b  = (const float*)d_in[22];
    const float* lin2_w  = (const float*)d_in[23];
    const float* lin2_b  = (const float*)d_in[24];
    const float* dn1_w   = (const float*)d_in[25];
    const float* dn1_b   = (const float*)d_in[26];
    const float* dn2_w   = (const float*)d_in[27];
    const float* dn2_b   = (const float*)d_in[28];
    const float* dn3_w   = (const float*)d_in[29];
    const float* dn3_b   = (const float*)d_in[30];
    const float* decn_w  = (const float*)d_in[31];
    const float* decn_b  = (const float*)d_in[32];

    float* out = (float*)d_out;
    float* ws  = (float*)d_ws;

    float* s_seq   = ws + (size_t) 0*SEQ;
    float* c_seq   = ws + (size_t) 1*SEQ;
    float* ps_seq  = ws + (size_t) 2*SEQ;
    float* pc_seq  = ws + (size_t) 3*SEQ;
    float* s_enc   = ws + (size_t) 4*SEQ;
    float* c_enc   = ws + (size_t) 5*SEQ;
    float* t1      = ws + (size_t) 8*SEQ;
    float* t2      = ws + (size_t) 9*SEQ;
    float* tgt     = ws + (size_t)10*SEQ;
    float* ffnout  = ws + (size_t)11*SEQ;
    float* xn      = ws + (size_t)12*SEQ;   // also yln, and final ln2 out
    float* ubuf    = ws + (size_t)13*SEQ;
    float* vbuf    = ws + (size_t)14*SEQ;
    float* vrev    = ws + (size_t)15*SEQ;
    float* xdbl    = ws + (size_t)16*SEQ;   // 4*1024*136
    float* ysbuf   = ws + (size_t)18*SEQ;   // 4*SEQ
    float* pooledT = ws + (size_t)16*SEQ;   // pre-VSS only
    float* pc18T   = ws + (size_t)18*SEQ;   // pre-VSS only
    float* ffn_mid = ws + (size_t)18*SEQ;   // post-VSS only
    float* yln     = xn;
    float* tgt3    = ubuf;

    auto gemm = [&](const float* A, const float* A2, const float* W,
                    const float* bias, const float* res1, const float* res2,
                    float* C, int M, int N, int K, int act, int mode){
        dim3 g((N + 63)/64, (M + 63)/64, mode == 1 ? 2 : 1);
        gemm_bf16_kernel<<<g, 256, 0, stream>>>(A, A2, W, bias, res1, res2,
                                                C, M, N, K, act, mode);
    };

    // x2 may be null: vss input is x (+x2); residual epilogue adds both.
    auto vss = [&](const float* x, const float* x2, int i, float* o){
        ln_kernel<<<256, 256, 0, stream>>>(x, x2, vln_w + i*512, vln_b + i*512,
                                           xn, MROWS, 0);
        gemm(xn, nullptr, vin_w + (size_t)i*512*512, vin_b + i*512,
             nullptr, nullptr, ubuf, MROWS, 512, 512, 0, 0);
        conv_gelu_kernel<<<SEQ/256, 256, 0, stream>>>(ubuf, vconv_w + (size_t)i*512*9,
                                                      vconv_b + i*512, vbuf, vrev);
        gemm(vbuf, vrev, vxproj_w + (size_t)i*4*136*512, nullptr,
             nullptr, nullptr, xdbl, MROWS, 272, 512, 0, 1);
        scan_kernel<<<2048, 256, 0, stream>>>(xdbl, vbuf, vrev,
                                              vdt_bias + i*32, vA_log + i*32, vD + i*32,
                                              ysbuf);
        combine_ln_kernel<<<256, 256, 0, stream>>>(ysbuf, von_w + i*512, von_b + i*512, yln);
        gemm(yln, nullptr, vout_w + (size_t)i*512*512, vout_b + i*512,
             x, x2, o, MROWS, 512, 512, 0, 0);
    };

    // ---- positional embedding path ----
    to_seq3_kernel<<<3*SEQ/256, 256, 0, stream>>>(style, content, pos_s,
                                                  s_seq, c_seq, ps_seq);
    pool_kernel<<<4*324, 256, 0, stream>>>(content, pooledT);
    gemm(pooledT, nullptr, newps_w, newps_b, nullptr, nullptr,
         pc18T, 4*324, 512, 512, 0, 0);
    resize_kernel<<<4*256, 256, 0, stream>>>(pc18T, pc_seq);

    // ---- encoders ----
    vss(s_seq, nullptr, 0, s_enc);
    vss(c_seq, nullptr, 1, c_enc);

    // ---- decoder ----
    vss(c_enc, pc_seq, 2, t1);       // t1 = vss(q) incl. residual q
    ln_kernel<<<256, 256, 0, stream>>>(c_enc, t1, dn1_w, dn1_b, tgt, MROWS, 0);
    vss(s_enc, ps_seq, 3, t2);
    ln_kernel<<<256, 256, 0, stream>>>(s_enc, t2, dn2_w, dn2_b, tgt, MROWS, 1);

    gemm(tgt, nullptr, lin1_w, lin1_b, nullptr, nullptr,
         ffn_mid, MROWS, 2048, 512, 1, 0);
    gemm(ffn_mid, nullptr, lin2_w, lin2_b, nullptr, nullptr,
         ffnout, MROWS, 512, 2048, 0, 0);
    ln2_kernel<<<256, 256, 0, stream>>>(tgt, ffnout, dn3_w, dn3_b,
                                        decn_w, decn_b, tgt3);
    from_seq_kernel<<<SEQ/256, 256, 0, stream>>>(tgt3, out);
}

// Round 3
// 383.002 us; speedup vs baseline: 2.9772x; 1.2364x over previous
//
#include <hip/hip_runtime.h>
#include <hip/hip_bf16.h>
#include <math.h>

// ---------------- problem constants ----------------
#define L_SEQ 256
#define BB    4
#define DD    512
#define SEQ   (L_SEQ*BB*DD)   // 524288
#define MROWS (L_SEQ*BB)      // 1024
#define NHEAD 8
#define DSTATE 64

typedef __hip_bfloat16 bfloat;
typedef __bf16 bfx8 __attribute__((ext_vector_type(8)));
typedef float f32x4 __attribute__((ext_vector_type(4)));

__device__ __forceinline__ float gelu_tanh(float x){
    float x3 = x*x*x;
    return 0.5f*x*(1.0f + tanhf(0.7978845608028654f*(x + 0.044715f*x3)));
}

__device__ __forceinline__ void glds16(const void* g, void* l){
    __builtin_amdgcn_global_load_lds(
        (const __attribute__((address_space(1))) unsigned int*)g,
        (__attribute__((address_space(3))) unsigned int*)l, 16, 0, 0);
}

// -------- weight fp32 -> bf16 conversion (6 jobs, float4-vectorized) --------
struct CvtArgs {
    const float* s[6];
    bfloat* d[6];
    int c4[6];   // cumulative float4 counts
};
__global__ void cvt_w_kernel(CvtArgs a, int total4){
    int i = blockIdx.x*256 + threadIdx.x;
    if (i >= total4) return;
    int j = 0, base = 0;
    while (j < 5 && i >= a.c4[j]) { base = a.c4[j]; ++j; }
    int k = i - base;
    float4 v = ((const float4*)a.s[j])[k];
    union { bfloat h[4]; ushort4 u; } o;
    o.h[0] = __float2bfloat16(v.x); o.h[1] = __float2bfloat16(v.y);
    o.h[2] = __float2bfloat16(v.z); o.h[3] = __float2bfloat16(v.w);
    *(ushort4*)(a.d[j] + (size_t)k*4) = o.u;
}

// style/content/pos_s -> sequence layout, one launch.
__global__ void to_seq3_kernel(const float* __restrict__ s, const float* __restrict__ c,
                               const float* __restrict__ p,
                               float* __restrict__ os, float* __restrict__ oc,
                               float* __restrict__ op){
    int idx = blockIdx.x*256 + threadIdx.x;
    int which = idx >> 19;
    int i = idx & (SEQ-1);
    const float* in = which==0 ? s : (which==1 ? c : p);
    float* o = which==0 ? os : (which==1 ? oc : op);
    int cc = i & 511;
    int b = (i >> 9) & 3;
    int l = i >> 11;
    o[i] = in[(b*512 + cc)*256 + l];
}

__global__ void from_seq_kernel(const float* __restrict__ in, float* __restrict__ out){
    int idx = blockIdx.x*256 + threadIdx.x;
    int l = idx & 255;
    int c = (idx >> 8) & 511;
    int b = idx >> 17;
    out[idx] = in[(l*4 + b)*512 + c];
}

// adaptive pool 16x16 -> 18x18, bf16 transposed out: pooledT[(b*324+ij)*512 + c]
__global__ void pool_kernel(const float* __restrict__ content, bfloat* __restrict__ pooledT){
    int bij = blockIdx.x;
    int b = bij / 324;
    int ij = bij % 324;
    int i = ij / 18, j = ij % 18;
    int s0 = (i*16)/18,  e0 = ((i+1)*16 + 17)/18;
    int s1 = (j*16)/18,  e1 = ((j+1)*16 + 17)/18;
    float inv = 1.0f / (float)((e0-s0)*(e1-s1));
    for (int c = threadIdx.x; c < 512; c += 256){
        float acc = 0.f;
        for (int h = s0; h < e0; ++h)
            for (int w = s1; w < e1; ++w)
                acc += content[((b*512 + c)*16 + h)*16 + w];
        pooledT[(size_t)(b*324 + ij)*512 + c] = __float2bfloat16(acc * inv);
    }
}

__device__ __forceinline__ int resize_taps(int o, float* w, int* j0_out){
    const float inv_scale = 18.0f/16.0f;
    float sf = (o + 0.5f)*inv_scale - 0.5f;
    int j0 = (int)ceilf(sf - inv_scale);
    int j1 = (int)floorf(sf + inv_scale);
    if (j0 < 0) j0 = 0;
    if (j1 > 17) j1 = 17;
    int n = j1 - j0 + 1;
    float sum = 0.f;
    for (int t = 0; t < n; ++t){
        float d = fabsf(sf - (float)(j0 + t)) * (16.0f/18.0f);
        float v = fmaxf(0.f, 1.f - d);
        w[t] = v; sum += v;
    }
    float r = 1.f / sum;
    for (int t = 0; t < n; ++t) w[t] *= r;
    *j0_out = j0;
    return n;
}

__global__ void resize_kernel(const float* __restrict__ pc18T, float* __restrict__ pc_seq){
    int bid = blockIdx.x;
    int b = bid >> 8;
    int yx = bid & 255;
    int y = yx >> 4, x = yx & 15;
    float wy[3], wx[3];
    int jy0, jx0;
    int ny = resize_taps(y, wy, &jy0);
    int nx = resize_taps(x, wx, &jx0);
    for (int c = threadIdx.x; c < 512; c += 256){
        float acc = 0.f;
        for (int ty = 0; ty < ny; ++ty)
            for (int tx = 0; tx < nx; ++tx)
                acc += wy[ty]*wx[tx] *
                       pc18T[(size_t)(b*324 + (jy0+ty)*18 + (jx0+tx))*512 + c];
        pc_seq[(size_t)((y*16 + x)*4 + b)*512 + c] = acc;
    }
}

// LayerNorm over 512. One wave/row. outf/outb nullable; accumulate reads outf.
__global__ __launch_bounds__(256) void ln_kernel(
    const float* __restrict__ in0, const float* __restrict__ in1,
    const float* __restrict__ w, const float* __restrict__ b,
    float* __restrict__ outf, bfloat* __restrict__ outb,
    int M, int accumulate)
{
    int wave = threadIdx.x >> 6;
    int lane = threadIdx.x & 63;
    int row = blockIdx.x*4 + wave;
    if (row >= M) return;
    const float* p0 = in0 + (size_t)row*512;
    const float* p1 = in1 ? in1 + (size_t)row*512 : nullptr;
    int base = lane*8;
    float v[8];
    #pragma unroll
    for (int t = 0; t < 8; ++t){
        v[t] = p0[base + t];
        if (p1) v[t] += p1[base + t];
    }
    float s = 0.f;
    #pragma unroll
    for (int t = 0; t < 8; ++t) s += v[t];
    #pragma unroll
    for (int off = 32; off > 0; off >>= 1) s += __shfl_xor(s, off, 64);
    float mean = s * (1.f/512.f);
    float sq = 0.f;
    #pragma unroll
    for (int t = 0; t < 8; ++t){ float d = v[t] - mean; sq += d*d; }
    #pragma unroll
    for (int off = 32; off > 0; off >>= 1) sq += __shfl_xor(sq, off, 64);
    float rstd = rsqrtf(sq * (1.f/512.f) + 1e-5f);
    #pragma unroll
    for (int t = 0; t < 8; ++t){
        float o = (v[t] - mean)*rstd*w[base + t] + b[base + t];
        size_t oi = (size_t)row*512 + base + t;
        if (accumulate) o += outf[oi];
        if (outf) outf[oi] = o;
        if (outb) outb[oi] = __float2bfloat16(o);
    }
}

// double-LN: y = LN(LN(in0+in1; w1,b1); w2,b2)
__global__ __launch_bounds__(256) void ln2_kernel(
    const float* __restrict__ in0, const float* __restrict__ in1,
    const float* __restrict__ w1, const float* __restrict__ b1,
    const float* __restrict__ w2, const float* __restrict__ b2,
    float* __restrict__ out)
{
    int wave = threadIdx.x >> 6;
    int lane = threadIdx.x & 63;
    int row = blockIdx.x*4 + wave;
    const float* p0 = in0 + (size_t)row*512;
    const float* p1 = in1 + (size_t)row*512;
    int base = lane*8;
    float v[8];
    #pragma unroll
    for (int t = 0; t < 8; ++t) v[t] = p0[base + t] + p1[base + t];
    float s = 0.f;
    #pragma unroll
    for (int t = 0; t < 8; ++t) s += v[t];
    #pragma unroll
    for (int off = 32; off > 0; off >>= 1) s += __shfl_xor(s, off, 64);
    float mean = s * (1.f/512.f);
    float sq = 0.f;
    #pragma unroll
    for (int t = 0; t < 8; ++t){ float d = v[t] - mean; sq += d*d; }
    #pragma unroll
    for (int off = 32; off > 0; off >>= 1) sq += __shfl_xor(sq, off, 64);
    float rstd = rsqrtf(sq * (1.f/512.f) + 1e-5f);
    #pragma unroll
    for (int t = 0; t < 8; ++t) v[t] = (v[t] - mean)*rstd*w1[base + t] + b1[base + t];
    s = 0.f;
    #pragma unroll
    for (int t = 0; t < 8; ++t) s += v[t];
    #pragma unroll
    for (int off = 32; off > 0; off >>= 1) s += __shfl_xor(s, off, 64);
    mean = s * (1.f/512.f);
    sq = 0.f;
    #pragma unroll
    for (int t = 0; t < 8; ++t){ float d = v[t] - mean; sq += d*d; }
    #pragma unroll
    for (int off = 32; off > 0; off >>= 1) sq += __shfl_xor(sq, off, 64);
    rstd = rsqrtf(sq * (1.f/512.f) + 1e-5f);
    #pragma unroll
    for (int t = 0; t < 8; ++t)
        out[(size_t)row*512 + base + t] = (v[t] - mean)*rstd*w2[base + t] + b2[base + t];
}

// depthwise conv (kw=1 only since W=1) + bias + gelu; fp32 + bf16, fwd + reversed.
__global__ void conv_gelu_kernel(const float* __restrict__ u,
    const float* __restrict__ cw, const float* __restrict__ cb,
    float* __restrict__ v, float* __restrict__ vrev,
    bfloat* __restrict__ vb, bfloat* __restrict__ vrb)
{
    int idx = blockIdx.x*256 + threadIdx.x;
    int d = idx & 511;
    int l = (idx >> 9) & 3;
    int bt = idx >> 11;
    float acc = cb[d];
    #pragma unroll
    for (int kh = 0; kh < 3; ++kh){
        int hh = l + kh - 1;
        if (hh >= 0 && hh < 4)
            acc += u[(size_t)(bt*4 + hh)*512 + d] * cw[(d*3 + kh)*3 + 1];
    }
    float g = gelu_tanh(acc);
    size_t rid = (size_t)(bt*4 + (3 - l))*512 + d;
    v[idx] = g;
    vrev[rid] = g;
    vb[idx] = __float2bfloat16(g);
    vrb[rid] = __float2bfloat16(g);
}

// ---------------- bf16 MFMA GEMM v2 (2-phase global_load_lds pipeline) -------
// C[M,N] = A[M,K]*W[N,K]^T (+bias)(+gelu)(+res1+res2); bf16 in, fp32 acc.
// 64x64 tile, BK=64, double-buffered LDS (32KB), XOR 16B-slot swizzle.
// mode==1 (xproj): z picks A/A2 and W += z*272*K; scatter to xdbl k-major.
__global__ __launch_bounds__(256) void gemm2_kernel(
    const bfloat* __restrict__ Abf, const bfloat* __restrict__ A2bf,
    const bfloat* __restrict__ Wbf, const float* __restrict__ bias,
    const float* __restrict__ res1, const float* __restrict__ res2,
    float* __restrict__ Cf, bfloat* __restrict__ Cb,
    int M, int N, int K, int nbn, int act, int mode)
{
    __shared__ __align__(16) char lds[32768];   // 2 bufs x (A 8KB + B 8KB)

    const int z = blockIdx.z;
    const bfloat* Ap = Abf;
    const bfloat* Wp = Wbf;
    if (mode == 1){ if (z) Ap = A2bf; Wp = Wbf + (size_t)z*272*K; }

    // bijective XCD swizzle (m204): consecutive wgid share the A row-panel
    int nwg = gridDim.x;
    int orig = blockIdx.x;
    int q = nwg >> 3, r = nwg & 7;
    int xcd = orig & 7, off = orig >> 3;
    int wgid = (xcd < r ? xcd*(q+1) : r*(q+1) + (xcd-r)*q) + off;
    int bm = (wgid / nbn) * 64;
    int bn = (wgid % nbn) * 64;

    const int tid = threadIdx.x;
    const int wv = tid >> 6, ln = tid & 63;

    // staging: thread -> row r0=tid>>3 (inst1: +32), swizzled source chunk
    const int r0 = tid >> 3;
    const int cs = (tid & 7) ^ (r0 & 7);     // same for both insts (+32 keeps &7)
    int ar0 = bm + r0;       if (ar0 > M-1) ar0 = M-1;
    int ar1 = bm + r0 + 32;  if (ar1 > M-1) ar1 = M-1;
    int br0 = bn + r0;       if (br0 > N-1) br0 = N-1;
    int br1 = bn + r0 + 32;  if (br1 > N-1) br1 = N-1;
    const bfloat* a0p = Ap + (size_t)ar0*K + cs*8;
    const bfloat* a1p = Ap + (size_t)ar1*K + cs*8;
    const bfloat* b0p = Wp + (size_t)br0*K + cs*8;
    const bfloat* b1p = Wp + (size_t)br1*K + cs*8;

    auto STAGE = [&](int bb, int k0){
        char* base = lds + bb*16384 + wv*1024;     // wave-uniform; +lane*16 by HW
        glds16(a0p + k0, base);                    // A rows 0..31
        glds16(a1p + k0, base + 4096);             // A rows 32..63
        glds16(b0p + k0, base + 8192);             // B rows 0..31
        glds16(b1p + k0, base + 12288);            // B rows 32..63
    };

    const int wr = wv >> 1, wc = wv & 1;
    const int fr = ln & 15, fc = ln >> 4;
    f32x4 acc[2][2] = {};

    auto COMP = [&](int bb){
        char* bA = lds + bb*16384;
        char* bB = bA + 8192;
        int ra0 = wr*32 + fr, ra1 = ra0 + 16;
        int rb0 = wc*32 + fr, rb1 = rb0 + 16;
        #pragma unroll
        for (int kk = 0; kk < 2; ++kk){
            int ch = kk*4 + fc;
            bfx8 a0 = *(const bfx8*)(bA + ra0*128 + ((ch ^ (ra0&7))<<4));
            bfx8 a1 = *(const bfx8*)(bA + ra1*128 + ((ch ^ (ra1&7))<<4));
            bfx8 b0 = *(const bfx8*)(bB + rb0*128 + ((ch ^ (rb0&7))<<4));
            bfx8 b1 = *(const bfx8*)(bB + rb1*128 + ((ch ^ (rb1&7))<<4));
            acc[0][0] = __builtin_amdgcn_mfma_f32_16x16x32_bf16(a0,b0,acc[0][0],0,0,0);
            acc[0][1] = __builtin_amdgcn_mfma_f32_16x16x32_bf16(a0,b1,acc[0][1],0,0,0);
            acc[1][0] = __builtin_amdgcn_mfma_f32_16x16x32_bf16(a1,b0,acc[1][0],0,0,0);
            acc[1][1] = __builtin_amdgcn_mfma_f32_16x16x32_bf16(a1,b1,acc[1][1],0,0,0);
        }
    };

    STAGE(0, 0);
    __syncthreads();                 // compiler drains vmcnt before s_barrier
    const int nt = K >> 6;
    for (int t = 0; t < nt; ++t){
        int cur = t & 1;
        if (t + 1 < nt) STAGE(cur ^ 1, (t+1) << 6);   // loads fly under MFMA
        COMP(cur);
        __syncthreads();
    }

    // epilogue: C/D map col=lane&15, row=(lane>>4)*4+reg
    int er = (ln >> 4) * 4;
    int ec = ln & 15;
    #pragma unroll
    for (int i = 0; i < 2; ++i)
    #pragma unroll
    for (int j = 0; j < 2; ++j)
    #pragma unroll
    for (int rr = 0; rr < 4; ++rr){
        int m = bm + wr*32 + i*16 + er + rr;
        int n = bn + wc*32 + j*16 + ec;
        if (m >= M || n >= N) continue;
        float v = acc[i][j][rr];
        if (bias) v += bias[n];
        if (act) v = gelu_tanh(v);
        if (res1) v += res1[(size_t)m*N + n];
        if (res2) v += res2[(size_t)m*N + n];
        if (mode == 1){
            int k2 = n >= 136;
            int cc = n - (k2 ? 136 : 0);
            Cf[((size_t)((z*2 + k2)*1024 + m))*136 + cc] = v;
        } else {
            if (Cf) Cf[(size_t)m*N + n] = v;
            if (Cb) Cb[(size_t)m*N + n] = __float2bfloat16(v);
        }
    }
}

// selective scan: 64 lanes per (bt,k,nh) head; L=4 steps, h[64] in regs.
__global__ __launch_bounds__(256) void scan_kernel(
    const float* __restrict__ xdbl,   // [4][1024][136]
    const float* __restrict__ v,      // [1024][512]
    const float* __restrict__ vrev,   // [1024][512]
    const float* __restrict__ dt_bias,
    const float* __restrict__ A_log,
    const float* __restrict__ Dp,
    float* __restrict__ ys)           // [256][4][4][512]
{
    __shared__ float Bs[4][64];
    __shared__ float Cs[4][64];
    int grp  = threadIdx.x >> 6;
    int lane = threadIdx.x & 63;
    int gid = blockIdx.x*4 + grp;
    int bt = gid >> 5;
    int k  = (gid >> 3) & 3;
    int nh = gid & 7;
    float A  = -expf(A_log[k*8 + nh]);
    float Dv = Dp[k*8 + nh];
    float dtb = dt_bias[k*8 + nh];
    const float* xsrc = (k < 2) ? v : vrev;
    float h[64];
    #pragma unroll
    for (int n = 0; n < 64; ++n) h[n] = 0.f;
    for (int l = 0; l < 4; ++l){
        const float* row = xdbl + (size_t)((k*1024 + bt*4 + l))*136;
        float draw = row[nh] + dtb;
        float dt = fmaxf(draw, 0.f) + log1pf(expf(-fabsf(draw)));
        float dA = expf(dt * A);
        __syncthreads();
        Bs[grp][lane] = row[8 + lane];
        Cs[grp][lane] = row[72 + lane];
        __syncthreads();
        float xd = xsrc[(size_t)(bt*4 + l)*512 + nh*64 + lane];
        float dtx = dt * xd;
        float y = 0.f;
        #pragma unroll
        for (int n = 0; n < 64; ++n){
            h[n] = h[n]*dA + dtx*Bs[grp][n];
            y += h[n]*Cs[grp][n];
        }
        ys[(size_t)((bt*4 + k)*4 + l)*512 + nh*64 + lane] = y + Dv*xd;
    }
}

// fused combine + LN, bf16 out (feeds vout GEMM)
__global__ __launch_bounds__(256) void combine_ln_kernel(
    const float* __restrict__ ys, const float* __restrict__ w,
    const float* __restrict__ b, bfloat* __restrict__ outb)
{
    int wave = threadIdx.x >> 6;
    int lane = threadIdx.x & 63;
    int row = blockIdx.x*4 + wave;     // bt*4 + l
    int bt = row >> 2, l = row & 3, rl = 3 - l;
    int base = lane*8;
    const float* y0 = ys + ((size_t)(bt*16 + 0 + l ))*512 + base;
    const float* y1 = ys + ((size_t)(bt*16 + 4 + l ))*512 + base;
    const float* y2 = ys + ((size_t)(bt*16 + 8 + rl))*512 + base;
    const float* y3 = ys + ((size_t)(bt*16 + 12 + rl))*512 + base;
    float v[8];
    #pragma unroll
    for (int t = 0; t < 8; ++t) v[t] = y0[t] + y1[t] + y2[t] + y3[t];
    float s = 0.f;
    #pragma unroll
    for (int t = 0; t < 8; ++t) s += v[t];
    #pragma unroll
    for (int off = 32; off > 0; off >>= 1) s += __shfl_xor(s, off, 64);
    float mean = s * (1.f/512.f);
    float sq = 0.f;
    #pragma unroll
    for (int t = 0; t < 8; ++t){ float d = v[t] - mean; sq += d*d; }
    #pragma unroll
    for (int off = 32; off > 0; off >>= 1) sq += __shfl_xor(sq, off, 64);
    float rstd = rsqrtf(sq * (1.f/512.f) + 1e-5f);
    #pragma unroll
    for (int t = 0; t < 8; ++t)
        outb[(size_t)row*512 + base + t] =
            __float2bfloat16((v[t] - mean)*rstd*w[base + t] + b[base + t]);
}

extern "C" void kernel_launch(void* const* d_in, const int* in_sizes, int n_in,
                              void* d_out, int out_size, void* d_ws, size_t ws_size,
                              hipStream_t stream)
{
    const float* style   = (const float*)d_in[0];
    const float* content = (const float*)d_in[2];
    const float* pos_s   = (const float*)d_in[4];
    const float* newps_w = (const float*)d_in[5];
    const float* newps_b = (const float*)d_in[6];
    const float* vln_w   = (const float*)d_in[7];
    const float* vln_b   = (const float*)d_in[8];
    const float* vin_w   = (const float*)d_in[9];
    const float* vin_b   = (const float*)d_in[10];
    const float* vconv_w = (const float*)d_in[11];
    const float* vconv_b = (const float*)d_in[12];
    const float* vxproj_w= (const float*)d_in[13];
    const float* vdt_bias= (const float*)d_in[14];
    const float* vA_log  = (const float*)d_in[15];
    const float* vD      = (const float*)d_in[16];
    const float* von_w   = (const float*)d_in[17];
    const float* von_b   = (const float*)d_in[18];
    const float* vout_w  = (const float*)d_in[19];
    const float* vout_b  = (const float*)d_in[20];
    const float* lin1_w  = (const float*)d_in[21];
    const float* lin1_b  = (const float*)d_in[22];
    const float* lin2_w  = (const float*)d_in[23];
    const float* lin2_b  = (const float*)d_in[24];
    const float* dn1_w   = (const float*)d_in[25];
    const float* dn1_b   = (const float*)d_in[26];
    const float* dn2_w   = (const float*)d_in[27];
    const float* dn2_b   = (const float*)d_in[28];
    const float* dn3_w   = (const float*)d_in[29];
    const float* dn3_b   = (const float*)d_in[30];
    const float* decn_w  = (const float*)d_in[31];
    const float* decn_b  = (const float*)d_in[32];

    float* out = (float*)d_out;
    float* ws  = (float*)d_ws;

    // ---- fp32 region: 20 SEQ = 40MB ----
    float* s_seq  = ws + (size_t) 0*SEQ;
    float* c_seq  = ws + (size_t) 1*SEQ;
    float* ps_seq = ws + (size_t) 2*SEQ;
    float* pc_seq = ws + (size_t) 3*SEQ;
    float* s_enc  = ws + (size_t) 4*SEQ;
    float* c_enc  = ws + (size_t) 5*SEQ;
    float* t1     = ws + (size_t) 6*SEQ;
    float* t2     = ws + (size_t) 7*SEQ;
    float* tgt    = ws + (size_t) 8*SEQ;
    float* ffnout = ws + (size_t) 9*SEQ;
    float* ubuf   = ws + (size_t)10*SEQ;
    float* vbuf   = ws + (size_t)11*SEQ;
    float* vrev   = ws + (size_t)12*SEQ;
    float* xdbl   = ws + (size_t)13*SEQ;   // 4*1024*136 = 557056 (spans 13-14)
    float* ysbuf  = ws + (size_t)15*SEQ;   // 4 SEQ (15-18)
    float* pc18T  = ws + (size_t)15*SEQ;   // pre-VSS only (663552)
    float* tgt3   = ubuf;

    // ---- bf16 region at 20 SEQ floats ----
    bfloat* wb = (bfloat*)(ws + (size_t)20*SEQ);
    bfloat* wb_vin    = wb;                         // 4*512*512
    bfloat* wb_xproj  = wb + 1048576;               // 4*4*136*512
    bfloat* wb_vout   = wb + 2162688;               // 4*512*512
    bfloat* wb_lin1   = wb + 3211264;               // 2048*512
    bfloat* wb_lin2   = wb + 4259840;               // 512*2048
    bfloat* wb_newps  = wb + 5308416;               // 512*512
    bfloat* xn_bf     = wb + 5570560;               // SEQ (also yln_bf)
    bfloat* vbuf_bf   = xn_bf  + (size_t)SEQ;
    bfloat* vrev_bf   = vbuf_bf+ (size_t)SEQ;
    bfloat* tgt_bf    = vrev_bf+ (size_t)SEQ;
    bfloat* ffn_bf    = tgt_bf + (size_t)SEQ;       // 1024*2048
    bfloat* pooled_bf = ffn_bf;                     // pre-VSS only (663552)

    auto gemm = [&](const bfloat* A, const bfloat* A2, const bfloat* W,
                    const float* bias, const float* res1, const float* res2,
                    float* Cf, bfloat* Cb, int M, int N, int K, int act, int mode){
        int nbm = (M + 63)/64, nbn = (N + 63)/64;
        dim3 g(nbm*nbn, 1, mode==1 ? 2 : 1);
        gemm2_kernel<<<g, 256, 0, stream>>>(A, A2, W, bias, res1, res2,
                                            Cf, Cb, M, N, K, nbn, act, mode);
    };

    auto vss = [&](const float* x, const float* x2, int i, float* o){
        ln_kernel<<<256, 256, 0, stream>>>(x, x2, vln_w+i*512, vln_b+i*512,
                                           nullptr, xn_bf, MROWS, 0);
        gemm(xn_bf, nullptr, wb_vin + (size_t)i*262144, vin_b+i*512,
             nullptr, nullptr, ubuf, nullptr, MROWS, 512, 512, 0, 0);
        conv_gelu_kernel<<<SEQ/256, 256, 0, stream>>>(ubuf, vconv_w + (size_t)i*4608,
                                                      vconv_b+i*512, vbuf, vrev,
                                                      vbuf_bf, vrev_bf);
        gemm(vbuf_bf, vrev_bf, wb_xproj + (size_t)i*278528, nullptr,
             nullptr, nullptr, xdbl, nullptr, MROWS, 272, 512, 0, 1);
        scan_kernel<<<2048, 256, 0, stream>>>(xdbl, vbuf, vrev,
                                              vdt_bias+i*32, vA_log+i*32, vD+i*32,
                                              ysbuf);
        combine_ln_kernel<<<256, 256, 0, stream>>>(ysbuf, von_w+i*512, von_b+i*512,
                                                   xn_bf);   // reuse as yln_bf
        gemm(xn_bf, nullptr, wb_vout + (size_t)i*262144, vout_b+i*512,
             x, x2, o, nullptr, MROWS, 512, 512, 0, 0);
    };

    // ---- weight conversion ----
    CvtArgs ca;
    ca.s[0]=vin_w;    ca.d[0]=wb_vin;
    ca.s[1]=vxproj_w; ca.d[1]=wb_xproj;
    ca.s[2]=vout_w;   ca.d[2]=wb_vout;
    ca.s[3]=lin1_w;   ca.d[3]=wb_lin1;
    ca.s[4]=lin2_w;   ca.d[4]=wb_lin2;
    ca.s[5]=newps_w;  ca.d[5]=wb_newps;
    ca.c4[0]=262144; ca.c4[1]=540672; ca.c4[2]=802816;
    ca.c4[3]=1064960; ca.c4[4]=1327104; ca.c4[5]=1392640;
    cvt_w_kernel<<<(1392640+255)/256, 256, 0, stream>>>(ca, 1392640);

    // ---- positional embedding path ----
    to_seq3_kernel<<<3*SEQ/256, 256, 0, stream>>>(style, content, pos_s,
                                                  s_seq, c_seq, ps_seq);
    pool_kernel<<<4*324, 256, 0, stream>>>(content, pooled_bf);
    gemm(pooled_bf, nullptr, wb_newps, newps_b, nullptr, nullptr,
         pc18T, nullptr, 1296, 512, 512, 0, 0);
    resize_kernel<<<4*256, 256, 0, stream>>>(pc18T, pc_seq);

    // ---- encoders ----
    vss(s_seq, nullptr, 0, s_enc);
    vss(c_seq, nullptr, 1, c_enc);

    // ---- decoder ----
    vss(c_enc, pc_seq, 2, t1);
    ln_kernel<<<256, 256, 0, stream>>>(c_enc, t1, dn1_w, dn1_b, tgt, nullptr, MROWS, 0);
    vss(s_enc, ps_seq, 3, t2);
    ln_kernel<<<256, 256, 0, stream>>>(s_enc, t2, dn2_w, dn2_b, tgt, tgt_bf, MROWS, 1);

    gemm(tgt_bf, nullptr, wb_lin1, lin1_b, nullptr, nullptr,
         nullptr, ffn_bf, MROWS, 2048, 512, 1, 0);
    gemm(ffn_bf, nullptr, wb_lin2, lin2_b, nullptr, nullptr,
         ffnout, nullptr, MROWS, 512, 2048, 0, 0);
    ln2_kernel<<<256, 256, 0, stream>>>(tgt, ffnout, dn3_w, dn3_b,
                                        decn_w, decn_b, tgt3);
    from_seq_kernel<<<SEQ/256, 256, 0, stream>>>(tgt3, out);
}

// Round 4
// 281.769 us; speedup vs baseline: 4.0469x; 1.3593x over previous
//
#include <hip/hip_runtime.h>
#include <hip/hip_bf16.h>
#include <math.h>

// ---------------- problem constants ----------------
#define SEQ   524288          // 256*4*512 floats per sequence tensor
#define MROWS 1024            // 256*4 rows of 512
#define XDBL_P 557056         // 4*1024*136 per pair element

typedef __hip_bfloat16 bfloat;
typedef __bf16 bfx8 __attribute__((ext_vector_type(8)));
typedef float f32x4 __attribute__((ext_vector_type(4)));

__device__ __forceinline__ float gelu_tanh(float x){
    float x3 = x*x*x;
    return 0.5f*x*(1.0f + tanhf(0.7978845608028654f*(x + 0.044715f*x3)));
}

__device__ __forceinline__ unsigned short bfbits(float x){
    union { __hip_bfloat16 h; unsigned short u; } cv;
    cv.h = __float2bfloat16(x);
    return cv.u;
}

__device__ __forceinline__ void glds16(const void* g, void* l){
    __builtin_amdgcn_global_load_lds(
        (const __attribute__((address_space(1))) unsigned int*)g,
        (__attribute__((address_space(3))) unsigned int*)l, 16, 0, 0);
}

// wave-level LN stats over v[8] (64 lanes * 8 = 512)
__device__ __forceinline__ void ln_stats(const float* v, float& mean, float& rstd){
    float s = 0.f;
    #pragma unroll
    for (int t = 0; t < 8; ++t) s += v[t];
    #pragma unroll
    for (int off = 32; off > 0; off >>= 1) s += __shfl_xor(s, off, 64);
    mean = s * (1.f/512.f);
    float sq = 0.f;
    #pragma unroll
    for (int t = 0; t < 8; ++t){ float d = v[t] - mean; sq += d*d; }
    #pragma unroll
    for (int off = 32; off > 0; off >>= 1) sq += __shfl_xor(sq, off, 64);
    rstd = rsqrtf(sq * (1.f/512.f) + 1e-5f);
}

// -------- weight fp32 -> bf16 conversion --------
struct CvtArgs {
    const float* s[6];
    bfloat* d[6];
    int c4[6];
};
__global__ void cvt_w_kernel(CvtArgs a, int total4){
    int i = blockIdx.x*256 + threadIdx.x;
    if (i >= total4) return;
    int j = 0, base = 0;
    while (j < 5 && i >= a.c4[j]) { base = a.c4[j]; ++j; }
    int k = i - base;
    float4 v = ((const float4*)a.s[j])[k];
    union { bfloat h[4]; ushort4 u; } o;
    o.h[0] = __float2bfloat16(v.x); o.h[1] = __float2bfloat16(v.y);
    o.h[2] = __float2bfloat16(v.z); o.h[3] = __float2bfloat16(v.w);
    *(ushort4*)(a.d[j] + (size_t)k*4) = o.u;
}

// LDS-tiled transpose: (b,c,l) -> seq[(l*4+b)*512+c], 3 tensors.
__global__ void to_seq3_kernel(const float* __restrict__ s, const float* __restrict__ c,
                               const float* __restrict__ p,
                               float* __restrict__ os, float* __restrict__ oc,
                               float* __restrict__ op){
    __shared__ float t[32][33];
    int blk = blockIdx.x;            // [3][4][16][8]
    int lt = blk & 7;  blk >>= 3;
    int ct = blk & 15; blk >>= 4;
    int b  = blk & 3;  blk >>= 2;
    const float* in = blk==0 ? s : (blk==1 ? c : p);
    float* o = blk==0 ? os : (blk==1 ? oc : op);
    int c0 = ct*32, l0 = lt*32;
    int lx = threadIdx.x & 31, g = threadIdx.x >> 5;
    #pragma unroll
    for (int q = 0; q < 4; ++q){
        int cy = g + q*8;
        t[cy][lx] = in[(size_t)(b*512 + c0+cy)*256 + l0 + lx];
    }
    __syncthreads();
    #pragma unroll
    for (int q = 0; q < 4; ++q){
        int ly = g + q*8;
        o[((size_t)(l0+ly)*4 + b)*512 + c0 + lx] = t[lx][ly];
    }
}

__global__ void from_seq_kernel(const float* __restrict__ in, float* __restrict__ out){
    int idx = blockIdx.x*256 + threadIdx.x;
    int l = idx & 255;
    int c = (idx >> 8) & 511;
    int b = idx >> 17;
    out[idx] = in[(size_t)(l*4 + b)*512 + c];
}

// adaptive pool 16x16 -> 18x18, bf16 transposed out
__global__ void pool_kernel(const float* __restrict__ content, bfloat* __restrict__ pooledT){
    int bij = blockIdx.x;
    int b = bij / 324;
    int ij = bij % 324;
    int i = ij / 18, j = ij % 18;
    int s0 = (i*16)/18,  e0 = ((i+1)*16 + 17)/18;
    int s1 = (j*16)/18,  e1 = ((j+1)*16 + 17)/18;
    float inv = 1.0f / (float)((e0-s0)*(e1-s1));
    for (int c = threadIdx.x; c < 512; c += 256){
        float acc = 0.f;
        for (int h = s0; h < e0; ++h)
            for (int w = s1; w < e1; ++w)
                acc += content[((b*512 + c)*16 + h)*16 + w];
        pooledT[(size_t)(b*324 + ij)*512 + c] = __float2bfloat16(acc * inv);
    }
}

__device__ __forceinline__ int resize_taps(int o, float* w, int* j0_out){
    const float inv_scale = 18.0f/16.0f;
    float sf = (o + 0.5f)*inv_scale - 0.5f;
    int j0 = (int)ceilf(sf - inv_scale);
    int j1 = (int)floorf(sf + inv_scale);
    if (j0 < 0) j0 = 0;
    if (j1 > 17) j1 = 17;
    int n = j1 - j0 + 1;
    float sum = 0.f;
    for (int t = 0; t < n; ++t){
        float d = fabsf(sf - (float)(j0 + t)) * (16.0f/18.0f);
        float v = fmaxf(0.f, 1.f - d);
        w[t] = v; sum += v;
    }
    float r = 1.f / sum;
    for (int t = 0; t < n; ++t) w[t] *= r;
    *j0_out = j0;
    return n;
}

__global__ void resize_kernel(const float* __restrict__ pc18T, float* __restrict__ pc_seq){
    int bid = blockIdx.x;
    int b = bid >> 8;
    int yx = bid & 255;
    int y = yx >> 4, x = yx & 15;
    float wy[3], wx[3];
    int jy0, jx0;
    int ny = resize_taps(y, wy, &jy0);
    int nx = resize_taps(x, wx, &jx0);
    for (int c = threadIdx.x; c < 512; c += 256){
        float acc = 0.f;
        for (int ty = 0; ty < ny; ++ty)
            for (int tx = 0; tx < nx; ++tx)
                acc += wy[ty]*wx[tx] *
                       pc18T[(size_t)(b*324 + (jy0+ty)*18 + (jx0+tx))*512 + c];
        pc_seq[(size_t)((y*16 + x)*4 + b)*512 + c] = acc;
    }
}

// pair LN at VSS entry: rows 0..2047, p=row>>10 picks (x,x2,weights[ibase+p])
__global__ __launch_bounds__(256) void ln_vss_pair_kernel(
    const float* __restrict__ x0, const float* __restrict__ x20,
    const float* __restrict__ x1, const float* __restrict__ x21,
    const float* __restrict__ wall, const float* __restrict__ ball,
    int ibase, bfloat* __restrict__ outb)
{
    int row = blockIdx.x*4 + (threadIdx.x >> 6);
    int lane = threadIdx.x & 63;
    int p = row >> 10, r2 = row & 1023;
    const float* in0 = (p ? x1 : x0) + (size_t)r2*512;
    const float* in1 = p ? x21 : x20;
    const float* w = wall + (ibase+p)*512;
    const float* b = ball + (ibase+p)*512;
    int base = lane*8;
    float v[8];
    #pragma unroll
    for (int t = 0; t < 8; ++t){
        v[t] = in0[base + t];
        if (in1) v[t] += in1[(size_t)r2*512 + base + t];
    }
    float mean, rstd;
    ln_stats(v, mean, rstd);
    bfloat* o = outb + (size_t)p*SEQ + (size_t)r2*512 + base;
    union { ushort u[8]; uint4 q; } pk;
    #pragma unroll
    for (int t = 0; t < 8; ++t)
        pk.u[t] = bfbits((v[t] - mean)*rstd*w[base + t] + b[base + t]);
    *(uint4*)o = pk.q;
}

// tgt = LN(a0+a1; w1,b1) + LN(c0+c1; w2,b2); fp32 + bf16 out
__global__ __launch_bounds__(256) void dn_pair_kernel(
    const float* __restrict__ a0, const float* __restrict__ a1,
    const float* __restrict__ w1, const float* __restrict__ b1,
    const float* __restrict__ c0, const float* __restrict__ c1,
    const float* __restrict__ w2, const float* __restrict__ b2,
    float* __restrict__ outf, bfloat* __restrict__ outb)
{
    int row = blockIdx.x*4 + (threadIdx.x >> 6);
    int lane = threadIdx.x & 63;
    int base = lane*8;
    size_t ro = (size_t)row*512 + base;
    float va[8], vc[8];
    #pragma unroll
    for (int t = 0; t < 8; ++t){ va[t] = a0[ro-base+base+t] + a1[ro+t-0]; }
    #pragma unroll
    for (int t = 0; t < 8; ++t){ va[t] = a0[ro+t] + a1[ro+t]; vc[t] = c0[ro+t] + c1[ro+t]; }
    float m1, r1, m2, r2;
    ln_stats(va, m1, r1);
    ln_stats(vc, m2, r2);
    union { ushort u[8]; uint4 q; } pk;
    #pragma unroll
    for (int t = 0; t < 8; ++t){
        float o = (va[t]-m1)*r1*w1[base+t] + b1[base+t]
                + (vc[t]-m2)*r2*w2[base+t] + b2[base+t];
        outf[ro + t] = o;
        pk.u[t] = bfbits(o);
    }
    *(uint4*)(outb + ro) = pk.q;
}

// double-LN: y = LN(LN(in0+in1; w1,b1); w2,b2)
__global__ __launch_bounds__(256) void ln2_kernel(
    const float* __restrict__ in0, const float* __restrict__ in1,
    const float* __restrict__ w1, const float* __restrict__ b1,
    const float* __restrict__ w2, const float* __restrict__ b2,
    float* __restrict__ out)
{
    int row = blockIdx.x*4 + (threadIdx.x >> 6);
    int lane = threadIdx.x & 63;
    int base = lane*8;
    size_t ro = (size_t)row*512 + base;
    float v[8];
    #pragma unroll
    for (int t = 0; t < 8; ++t) v[t] = in0[ro+t] + in1[ro+t];
    float mean, rstd;
    ln_stats(v, mean, rstd);
    #pragma unroll
    for (int t = 0; t < 8; ++t) v[t] = (v[t]-mean)*rstd*w1[base+t] + b1[base+t];
    ln_stats(v, mean, rstd);
    #pragma unroll
    for (int t = 0; t < 8; ++t)
        out[ro + t] = (v[t]-mean)*rstd*w2[base+t] + b2[base+t];
}

// ---------------- bf16 MFMA GEMM, multi-job (blockIdx.z) ----------------
struct GJob {
    const bfloat* A; const bfloat* W;
    const float* bias; const float* res1; const float* res2;
    float* Cf; bfloat* Cb;
    const float* cw; const float* cb;               // epi==2 conv
    float* v; float* vr; bfloat* vb; bfloat* vrb;   // epi==2 outputs
};

// epi: 0 plain, 1 gelu, 2 conv+gelu dual-write (M=1024,N=512), 3 xproj scatter (N=272)
__global__ __launch_bounds__(256) void gemm3_kernel(
    GJob J0, GJob J1, GJob J2, GJob J3,
    int M, int N, int K, int nbn, int epi)
{
    __shared__ __align__(16) char lds[32768];
    const int z = blockIdx.z;
    GJob j = (z==0) ? J0 : (z==1) ? J1 : (z==2) ? J2 : J3;

    // bijective XCD swizzle (m204)
    int nwg = gridDim.x;
    int orig = blockIdx.x;
    int q = nwg >> 3, r = nwg & 7;
    int xcd = orig & 7, off = orig >> 3;
    int wgid = (xcd < r ? xcd*(q+1) : r*(q+1) + (xcd-r)*q) + off;
    int bm = (wgid / nbn) * 64;
    int bn = (wgid % nbn) * 64;

    const int tid = threadIdx.x;
    const int wv = tid >> 6, ln = tid & 63;

    const int r0 = tid >> 3;
    const int cs = (tid & 7) ^ (r0 & 7);
    int ar0 = bm + r0;       if (ar0 > M-1) ar0 = M-1;
    int ar1 = bm + r0 + 32;  if (ar1 > M-1) ar1 = M-1;
    int br0 = bn + r0;       if (br0 > N-1) br0 = N-1;
    int br1 = bn + r0 + 32;  if (br1 > N-1) br1 = N-1;
    const bfloat* a0p = j.A + (size_t)ar0*K + cs*8;
    const bfloat* a1p = j.A + (size_t)ar1*K + cs*8;
    const bfloat* b0p = j.W + (size_t)br0*K + cs*8;
    const bfloat* b1p = j.W + (size_t)br1*K + cs*8;

    auto STAGE = [&](int bb, int k0){
        char* base = lds + bb*16384 + wv*1024;
        glds16(a0p + k0, base);
        glds16(a1p + k0, base + 4096);
        glds16(b0p + k0, base + 8192);
        glds16(b1p + k0, base + 12288);
    };

    const int wr = wv >> 1, wc = wv & 1;
    const int fr = ln & 15, fc = ln >> 4;
    f32x4 acc[2][2] = {};

    auto COMP = [&](int bb){
        char* bA = lds + bb*16384;
        char* bB = bA + 8192;
        int ra0 = wr*32 + fr, ra1 = ra0 + 16;
        int rb0 = wc*32 + fr, rb1 = rb0 + 16;
        #pragma unroll
        for (int kk = 0; kk < 2; ++kk){
            int ch = kk*4 + fc;
            bfx8 a0 = *(const bfx8*)(bA + ra0*128 + ((ch ^ (ra0&7))<<4));
            bfx8 a1 = *(const bfx8*)(bA + ra1*128 + ((ch ^ (ra1&7))<<4));
            bfx8 b0 = *(const bfx8*)(bB + rb0*128 + ((ch ^ (rb0&7))<<4));
            bfx8 b1 = *(const bfx8*)(bB + rb1*128 + ((ch ^ (rb1&7))<<4));
            acc[0][0] = __builtin_amdgcn_mfma_f32_16x16x32_bf16(a0,b0,acc[0][0],0,0,0);
            acc[0][1] = __builtin_amdgcn_mfma_f32_16x16x32_bf16(a0,b1,acc[0][1],0,0,0);
            acc[1][0] = __builtin_amdgcn_mfma_f32_16x16x32_bf16(a1,b0,acc[1][0],0,0,0);
            acc[1][1] = __builtin_amdgcn_mfma_f32_16x16x32_bf16(a1,b1,acc[1][1],0,0,0);
        }
    };

    STAGE(0, 0);
    __syncthreads();
    const int nt = K >> 6;
    for (int t = 0; t < nt; ++t){
        int cur = t & 1;
        if (t + 1 < nt) STAGE(cur ^ 1, (t+1) << 6);
        COMP(cur);
        __syncthreads();
    }

    const int er = (ln >> 4) * 4;
    const int ec = ln & 15;

    if (epi == 2){
        // full tiles (M=1024,N=512). u = acc+bias -> LDS, conv along l, gelu, dual write.
        float* ut = (float*)lds;
        #pragma unroll
        for (int i = 0; i < 2; ++i)
        #pragma unroll
        for (int jj = 0; jj < 2; ++jj)
        #pragma unroll
        for (int rr = 0; rr < 4; ++rr){
            int ml = wr*32 + i*16 + er + rr;
            int nl = wc*32 + jj*16 + ec;
            ut[ml*65 + nl] = acc[i][jj][rr] + j.bias[bn + nl];
        }
        __syncthreads();
        int rrow = tid >> 2, c0 = (tid & 3) * 16;
        int bt4 = rrow & ~3, lv = rrow & 3;
        int m = bm + rrow;
        int mrev = bm + bt4 + 3 - lv;
        float g[16];
        #pragma unroll
        for (int c = 0; c < 16; ++c){
            int n = bn + c0 + c;
            float a = j.cb[n];
            #pragma unroll
            for (int kh = 0; kh < 3; ++kh){
                int hh = lv + kh - 1;
                if (hh >= 0 && hh < 4)
                    a += ut[(bt4 + hh)*65 + c0 + c] * j.cw[(n*3 + kh)*3 + 1];
            }
            g[c] = gelu_tanh(a);
        }
        #pragma unroll
        for (int c = 0; c < 16; c += 4){
            float4 f = make_float4(g[c], g[c+1], g[c+2], g[c+3]);
            *(float4*)(j.v  + (size_t)m   *512 + bn + c0 + c) = f;
            *(float4*)(j.vr + (size_t)mrev*512 + bn + c0 + c) = f;
        }
        union { ushort u[8]; uint4 qv; } pk;
        #pragma unroll
        for (int h = 0; h < 2; ++h){
            #pragma unroll
            for (int t = 0; t < 8; ++t) pk.u[t] = bfbits(g[h*8 + t]);
            *(uint4*)(j.vb  + (size_t)m   *512 + bn + c0 + h*8) = pk.qv;
            *(uint4*)(j.vrb + (size_t)mrev*512 + bn + c0 + h*8) = pk.qv;
        }
        return;
    }

    #pragma unroll
    for (int i = 0; i < 2; ++i)
    #pragma unroll
    for (int jj = 0; jj < 2; ++jj)
    #pragma unroll
    for (int rr = 0; rr < 4; ++rr){
        int m = bm + wr*32 + i*16 + er + rr;
        int n = bn + wc*32 + jj*16 + ec;
        if (m >= M || n >= N) continue;
        float v = acc[i][jj][rr];
        if (j.bias) v += j.bias[n];
        if (epi == 1) v = gelu_tanh(v);
        if (j.res1) v += j.res1[(size_t)m*N + n];
        if (j.res2) v += j.res2[(size_t)m*N + n];
        if (epi == 3){
            int k2 = n >= 136;
            int cc = n - (k2 ? 136 : 0);
            j.Cf[((size_t)(k2*1024 + m))*136 + cc] = v;
        } else {
            if (j.Cf) j.Cf[(size_t)m*N + n] = v;
            if (j.Cb) j.Cb[(size_t)m*N + n] = __float2bfloat16(v);
        }
    }
}

// selective scan, pair-batched: 16384 heads, 64 lanes each.
__global__ __launch_bounds__(256) void scan_kernel(
    const float* __restrict__ xdbl,   // [2][4][1024][136]
    const float* __restrict__ v,      // [2][1024][512]
    const float* __restrict__ vrev,
    const float* __restrict__ dt_bias, // + ibase*32 pre-added
    const float* __restrict__ A_log,
    const float* __restrict__ Dp,
    float* __restrict__ ys)           // [2][256][4][4][512]
{
    __shared__ float Bs[4][64];
    __shared__ float Cs[4][64];
    int grp  = threadIdx.x >> 6;
    int lane = threadIdx.x & 63;
    int gid = blockIdx.x*4 + grp;     // 0..16383
    int p  = gid >> 13;
    int g2 = gid & 8191;
    int bt = g2 >> 5;
    int k  = (g2 >> 3) & 3;
    int nh = g2 & 7;
    float A  = -expf(A_log[p*32 + k*8 + nh]);
    float Dv = Dp[p*32 + k*8 + nh];
    float dtb = dt_bias[p*32 + k*8 + nh];
    const float* xsrc = ((k < 2) ? v : vrev) + (size_t)p*SEQ;
    const float* xd_base = xdbl + (size_t)p*XDBL_P;
    float* ys_p = ys + (size_t)p*4*SEQ;
    float h[64];
    #pragma unroll
    for (int n = 0; n < 64; ++n) h[n] = 0.f;
    for (int l = 0; l < 4; ++l){
        const float* row = xd_base + (size_t)(k*1024 + bt*4 + l)*136;
        float draw = row[nh] + dtb;
        float dt = fmaxf(draw, 0.f) + log1pf(expf(-fabsf(draw)));
        float dA = expf(dt * A);
        __syncthreads();
        Bs[grp][lane] = row[8 + lane];
        Cs[grp][lane] = row[72 + lane];
        __syncthreads();
        float xd = xsrc[(size_t)(bt*4 + l)*512 + nh*64 + lane];
        float dtx = dt * xd;
        float y = 0.f;
        #pragma unroll
        for (int n = 0; n < 64; ++n){
            h[n] = h[n]*dA + dtx*Bs[grp][n];
            y += h[n]*Cs[grp][n];
        }
        ys_p[(size_t)((bt*4 + k)*4 + l)*512 + nh*64 + lane] = y + Dv*xd;
    }
}

// pair combine + LN -> bf16 yln
__global__ __launch_bounds__(256) void combine_ln_kernel(
    const float* __restrict__ ys, const float* __restrict__ wall,
    const float* __restrict__ ball, int ibase, bfloat* __restrict__ outb)
{
    int row = blockIdx.x*4 + (threadIdx.x >> 6);   // 0..2047
    int lane = threadIdx.x & 63;
    int p = row >> 10, r2 = row & 1023;
    int bt = r2 >> 2, l = r2 & 3, rl = 3 - l;
    int base = lane*8;
    const float* ys_p = ys + (size_t)p*4*SEQ;
    const float* y0 = ys_p + ((size_t)(bt*16 + 0  + l ))*512 + base;
    const float* y1 = ys_p + ((size_t)(bt*16 + 4  + l ))*512 + base;
    const float* y2 = ys_p + ((size_t)(bt*16 + 8  + rl))*512 + base;
    const float* y3 = ys_p + ((size_t)(bt*16 + 12 + rl))*512 + base;
    float v[8];
    #pragma unroll
    for (int t = 0; t < 8; ++t) v[t] = y0[t] + y1[t] + y2[t] + y3[t];
    float mean, rstd;
    ln_stats(v, mean, rstd);
    const float* w = wall + (ibase+p)*512;
    const float* b = ball + (ibase+p)*512;
    union { ushort u[8]; uint4 qv; } pk;
    #pragma unroll
    for (int t = 0; t < 8; ++t)
        pk.u[t] = bfbits((v[t]-mean)*rstd*w[base+t] + b[base+t]);
    *(uint4*)(outb + (size_t)p*SEQ + (size_t)r2*512 + base) = pk.qv;
}

extern "C" void kernel_launch(void* const* d_in, const int* in_sizes, int n_in,
                              void* d_out, int out_size, void* d_ws, size_t ws_size,
                              hipStream_t stream)
{
    const float* style   = (const float*)d_in[0];
    const float* content = (const float*)d_in[2];
    const float* pos_s   = (const float*)d_in[4];
    const float* newps_w = (const float*)d_in[5];
    const float* newps_b = (const float*)d_in[6];
    const float* vln_w   = (const float*)d_in[7];
    const float* vln_b   = (const float*)d_in[8];
    const float* vin_b   = (const float*)d_in[10];
    const float* vconv_w = (const float*)d_in[11];
    const float* vconv_b = (const float*)d_in[12];
    const float* vdt_bias= (const float*)d_in[14];
    const float* vA_log  = (const float*)d_in[15];
    const float* vD      = (const float*)d_in[16];
    const float* von_w   = (const float*)d_in[17];
    const float* von_b   = (const float*)d_in[18];
    const float* vout_b  = (const float*)d_in[20];
    const float* lin1_b  = (const float*)d_in[22];
    const float* lin2_b  = (const float*)d_in[24];
    const float* dn1_w   = (const float*)d_in[25];
    const float* dn1_b   = (const float*)d_in[26];
    const float* dn2_w   = (const float*)d_in[27];
    const float* dn2_b   = (const float*)d_in[28];
    const float* dn3_w   = (const float*)d_in[29];
    const float* dn3_b   = (const float*)d_in[30];
    const float* decn_w  = (const float*)d_in[31];
    const float* decn_b  = (const float*)d_in[32];

    float* out = (float*)d_out;
    float* ws  = (float*)d_ws;

    // ---- fp32 region: 25 SEQ ----
    float* s_seq  = ws + (size_t) 0*SEQ;
    float* c_seq  = ws + (size_t) 1*SEQ;
    float* ps_seq = ws + (size_t) 2*SEQ;
    float* pc_seq = ws + (size_t) 3*SEQ;
    float* s_enc  = ws + (size_t) 4*SEQ;
    float* c_enc  = ws + (size_t) 5*SEQ;
    float* t1     = ws + (size_t) 6*SEQ;
    float* t2     = ws + (size_t) 7*SEQ;
    float* tgt    = ws + (size_t) 8*SEQ;
    float* ffnout = ws + (size_t) 9*SEQ;
    float* vbuf   = ws + (size_t)10*SEQ;   // [2][SEQ]
    float* vrev   = ws + (size_t)12*SEQ;   // [2][SEQ]
    float* xdbl   = ws + (size_t)14*SEQ;   // [2][557056] spans 14-16
    float* ysbuf  = ws + (size_t)17*SEQ;   // [2][4 SEQ] spans 17-24
    float* pc18T  = ws + (size_t)17*SEQ;   // pre-VSS only (663552)
    float* tgt3   = vbuf;                  // post-FFN only

    // ---- bf16 region at 25 SEQ floats ----
    bfloat* wb = (bfloat*)(ws + (size_t)25*SEQ);
    bfloat* wb_vin    = wb;                         // 4*512*512
    bfloat* wb_xproj  = wb + 1048576;               // 4*4*136*512
    bfloat* wb_vout   = wb + 2162688;
    bfloat* wb_lin1   = wb + 3211264;
    bfloat* wb_lin2   = wb + 4259840;
    bfloat* wb_newps  = wb + 5308416;
    bfloat* xn_bf     = wb + 5570560;               // [2][SEQ] (also yln pair)
    bfloat* vbuf_bf   = xn_bf   + (size_t)2*SEQ;    // [2][SEQ]
    bfloat* vrev_bf   = vbuf_bf + (size_t)2*SEQ;    // [2][SEQ]
    bfloat* tgt_bf    = vrev_bf + (size_t)2*SEQ;    // SEQ
    bfloat* ffn_bf    = tgt_bf  + (size_t)SEQ;      // 1024*2048
    bfloat* pooled_bf = ffn_bf;                     // pre-VSS only

    auto launch_gemm = [&](GJob* jobs, int nz, int M, int N, int K, int epi){
        int nbm = (M + 63)/64, nbn = (N + 63)/64;
        dim3 g(nbm*nbn, 1, nz);
        gemm3_kernel<<<g, 256, 0, stream>>>(jobs[0], jobs[nz>1?1:0],
                                            jobs[nz>2?2:0], jobs[nz>3?3:0],
                                            M, N, K, nbn, epi);
    };

    GJob Z = {};   // zero template

    // pair VSS: ibase in {0,2}; inputs x[2], x2[2] (nullable); outputs o[2]
    auto vss_pair = [&](const float* xa, const float* x2a,
                        const float* xb, const float* x2b,
                        int ibase, float* oa, float* ob){
        ln_vss_pair_kernel<<<512, 256, 0, stream>>>(xa, x2a, xb, x2b,
                                                    vln_w, vln_b, ibase, xn_bf);
        GJob jv[2];
        for (int p = 0; p < 2; ++p){
            int i = ibase + p;
            jv[p] = Z;
            jv[p].A = xn_bf + (size_t)p*SEQ;
            jv[p].W = wb_vin + (size_t)i*262144;
            jv[p].bias = vin_b + i*512;
            jv[p].cw = vconv_w + (size_t)i*4608;
            jv[p].cb = vconv_b + i*512;
            jv[p].v   = vbuf + (size_t)p*SEQ;
            jv[p].vr  = vrev + (size_t)p*SEQ;
            jv[p].vb  = vbuf_bf + (size_t)p*SEQ;
            jv[p].vrb = vrev_bf + (size_t)p*SEQ;
        }
        launch_gemm(jv, 2, MROWS, 512, 512, 2);

        GJob jx[4];
        for (int zz = 0; zz < 4; ++zz){
            int p = zz >> 1, rev = zz & 1, i = ibase + p;
            jx[zz] = Z;
            jx[zz].A = (rev ? vrev_bf : vbuf_bf) + (size_t)p*SEQ;
            jx[zz].W = wb_xproj + (size_t)i*278528 + (size_t)rev*272*512;
            jx[zz].Cf = xdbl + (size_t)p*XDBL_P + (size_t)rev*278528;
        }
        launch_gemm(jx, 4, MROWS, 272, 512, 3);

        scan_kernel<<<4096, 256, 0, stream>>>(xdbl, vbuf, vrev,
                                              vdt_bias + ibase*32,
                                              vA_log + ibase*32,
                                              vD + ibase*32, ysbuf);
        combine_ln_kernel<<<512, 256, 0, stream>>>(ysbuf, von_w, von_b, ibase, xn_bf);

        GJob jo[2];
        const float* r1[2] = {xa, xb};
        const float* r2[2] = {x2a, x2b};
        float* oo[2] = {oa, ob};
        for (int p = 0; p < 2; ++p){
            int i = ibase + p;
            jo[p] = Z;
            jo[p].A = xn_bf + (size_t)p*SEQ;
            jo[p].W = wb_vout + (size_t)i*262144;
            jo[p].bias = vout_b + i*512;
            jo[p].res1 = r1[p];
            jo[p].res2 = r2[p];
            jo[p].Cf = oo[p];
        }
        launch_gemm(jo, 2, MROWS, 512, 512, 0);
    };

    // ---- weight conversion ----
    CvtArgs ca;
    ca.s[0]=(const float*)d_in[9];  ca.d[0]=wb_vin;
    ca.s[1]=(const float*)d_in[13]; ca.d[1]=wb_xproj;
    ca.s[2]=(const float*)d_in[19]; ca.d[2]=wb_vout;
    ca.s[3]=(const float*)d_in[21]; ca.d[3]=wb_lin1;
    ca.s[4]=(const float*)d_in[23]; ca.d[4]=wb_lin2;
    ca.s[5]=newps_w;                ca.d[5]=wb_newps;
    ca.c4[0]=262144; ca.c4[1]=540672; ca.c4[2]=802816;
    ca.c4[3]=1064960; ca.c4[4]=1327104; ca.c4[5]=1392640;
    cvt_w_kernel<<<(1392640+255)/256, 256, 0, stream>>>(ca, 1392640);

    // ---- positional path + layout ----
    to_seq3_kernel<<<1536, 256, 0, stream>>>(style, content, pos_s,
                                             s_seq, c_seq, ps_seq);
    pool_kernel<<<1296, 256, 0, stream>>>(content, pooled_bf);
    GJob jn = Z;
    jn.A = pooled_bf; jn.W = wb_newps; jn.bias = newps_b; jn.Cf = pc18T;
    launch_gemm(&jn, 1, 1296, 512, 512, 0);
    resize_kernel<<<1024, 256, 0, stream>>>(pc18T, pc_seq);

    // ---- encoders (pair) ----
    vss_pair(s_seq, nullptr, c_seq, nullptr, 0, s_enc, c_enc);

    // ---- decoders (pair) ----
    vss_pair(c_enc, pc_seq, s_enc, ps_seq, 2, t1, t2);
    dn_pair_kernel<<<256, 256, 0, stream>>>(c_enc, t1, dn1_w, dn1_b,
                                            s_enc, t2, dn2_w, dn2_b,
                                            tgt, tgt_bf);

    // ---- FFN + tail ----
    GJob jf = Z;
    jf.A = tgt_bf; jf.W = wb_lin1; jf.bias = lin1_b; jf.Cb = ffn_bf;
    launch_gemm(&jf, 1, MROWS, 2048, 512, 1);
    GJob jg = Z;
    jg.A = ffn_bf; jg.W = wb_lin2; jg.bias = lin2_b; jg.Cf = ffnout;
    launch_gemm(&jg, 1, MROWS, 512, 2048, 0);
    ln2_kernel<<<256, 256, 0, stream>>>(tgt, ffnout, dn3_w, dn3_b,
                                        decn_w, decn_b, tgt3);
    from_seq_kernel<<<SEQ/256, 256, 0, stream>>>(tgt3, out);
}

// Round 5
// 190.431 us; speedup vs baseline: 5.9879x; 1.4796x over previous
//
#include <hip/hip_runtime.h>
#include <hip/hip_bf16.h>
#include <math.h>

// ---------------- problem constants ----------------
#define SEQ   524288          // 256*4*512 floats per sequence tensor
#define MROWS 1024            // 256*4 rows of 512
#define XDBL_P 557056         // 4*1024*136 per pair element

typedef __hip_bfloat16 bfloat;
typedef __bf16 bfx8 __attribute__((ext_vector_type(8)));
typedef float f32x4 __attribute__((ext_vector_type(4)));

__device__ __forceinline__ float gelu_tanh(float x){
    float x3 = x*x*x;
    return 0.5f*x*(1.0f + tanhf(0.7978845608028654f*(x + 0.044715f*x3)));
}

__device__ __forceinline__ unsigned short bfbits(float x){
    union { __hip_bfloat16 h; unsigned short u; } cv;
    cv.h = __float2bfloat16(x);
    return cv.u;
}

__device__ __forceinline__ void glds16(const void* g, void* l){
    __builtin_amdgcn_global_load_lds(
        (const __attribute__((address_space(1))) unsigned int*)g,
        (__attribute__((address_space(3))) unsigned int*)l, 16, 0, 0);
}

// wave-level LN stats over v[8] (64 lanes * 8 = 512)
__device__ __forceinline__ void ln_stats(const float* v, float& mean, float& rstd){
    float s = 0.f;
    #pragma unroll
    for (int t = 0; t < 8; ++t) s += v[t];
    #pragma unroll
    for (int off = 32; off > 0; off >>= 1) s += __shfl_xor(s, off, 64);
    mean = s * (1.f/512.f);
    float sq = 0.f;
    #pragma unroll
    for (int t = 0; t < 8; ++t){ float d = v[t] - mean; sq += d*d; }
    #pragma unroll
    for (int off = 32; off > 0; off >>= 1) sq += __shfl_xor(sq, off, 64);
    rstd = rsqrtf(sq * (1.f/512.f) + 1e-5f);
}

// -------- weight fp32 -> bf16 conversion --------
struct CvtArgs {
    const float* s[6];
    bfloat* d[6];
    int c4[6];
};
__global__ void cvt_w_kernel(CvtArgs a, int total4){
    int i = blockIdx.x*256 + threadIdx.x;
    if (i >= total4) return;
    int j = 0, base = 0;
    while (j < 5 && i >= a.c4[j]) { base = a.c4[j]; ++j; }
    int k = i - base;
    float4 v = ((const float4*)a.s[j])[k];
    union { bfloat h[4]; ushort4 u; } o;
    o.h[0] = __float2bfloat16(v.x); o.h[1] = __float2bfloat16(v.y);
    o.h[2] = __float2bfloat16(v.z); o.h[3] = __float2bfloat16(v.w);
    *(ushort4*)(a.d[j] + (size_t)k*4) = o.u;
}

// LDS-tiled transpose: (b,c,l) -> seq[(l*4+b)*512+c], 3 tensors.
__global__ void to_seq3_kernel(const float* __restrict__ s, const float* __restrict__ c,
                               const float* __restrict__ p,
                               float* __restrict__ os, float* __restrict__ oc,
                               float* __restrict__ op){
    __shared__ float t[32][33];
    int blk = blockIdx.x;            // [3][4][16][8]
    int lt = blk & 7;  blk >>= 3;
    int ct = blk & 15; blk >>= 4;
    int b  = blk & 3;  blk >>= 2;
    const float* in = blk==0 ? s : (blk==1 ? c : p);
    float* o = blk==0 ? os : (blk==1 ? oc : op);
    int c0 = ct*32, l0 = lt*32;
    int lx = threadIdx.x & 31, g = threadIdx.x >> 5;
    #pragma unroll
    for (int q = 0; q < 4; ++q){
        int cy = g + q*8;
        t[cy][lx] = in[(size_t)(b*512 + c0+cy)*256 + l0 + lx];
    }
    __syncthreads();
    #pragma unroll
    for (int q = 0; q < 4; ++q){
        int ly = g + q*8;
        o[((size_t)(l0+ly)*4 + b)*512 + c0 + lx] = t[lx][ly];
    }
}

__global__ void from_seq_kernel(const float* __restrict__ in, float* __restrict__ out){
    int idx = blockIdx.x*256 + threadIdx.x;
    int l = idx & 255;
    int c = (idx >> 8) & 511;
    int b = idx >> 17;
    out[idx] = in[(size_t)(l*4 + b)*512 + c];
}

// adaptive pool 16x16 -> 18x18, bf16 transposed out
__global__ void pool_kernel(const float* __restrict__ content, bfloat* __restrict__ pooledT){
    int bij = blockIdx.x;
    int b = bij / 324;
    int ij = bij % 324;
    int i = ij / 18, j = ij % 18;
    int s0 = (i*16)/18,  e0 = ((i+1)*16 + 17)/18;
    int s1 = (j*16)/18,  e1 = ((j+1)*16 + 17)/18;
    float inv = 1.0f / (float)((e0-s0)*(e1-s1));
    for (int c = threadIdx.x; c < 512; c += 256){
        float acc = 0.f;
        for (int h = s0; h < e0; ++h)
            for (int w = s1; w < e1; ++w)
                acc += content[((b*512 + c)*16 + h)*16 + w];
        pooledT[(size_t)(b*324 + ij)*512 + c] = __float2bfloat16(acc * inv);
    }
}

__device__ __forceinline__ int resize_taps(int o, float* w, int* j0_out){
    const float inv_scale = 18.0f/16.0f;
    float sf = (o + 0.5f)*inv_scale - 0.5f;
    int j0 = (int)ceilf(sf - inv_scale);
    int j1 = (int)floorf(sf + inv_scale);
    if (j0 < 0) j0 = 0;
    if (j1 > 17) j1 = 17;
    int n = j1 - j0 + 1;
    float sum = 0.f;
    for (int t = 0; t < n; ++t){
        float d = fabsf(sf - (float)(j0 + t)) * (16.0f/18.0f);
        float v = fmaxf(0.f, 1.f - d);
        w[t] = v; sum += v;
    }
    float r = 1.f / sum;
    for (int t = 0; t < n; ++t) w[t] *= r;
    *j0_out = j0;
    return n;
}

__global__ void resize_kernel(const float* __restrict__ pc18T, float* __restrict__ pc_seq){
    int bid = blockIdx.x;
    int b = bid >> 8;
    int yx = bid & 255;
    int y = yx >> 4, x = yx & 15;
    float wy[3], wx[3];
    int jy0, jx0;
    int ny = resize_taps(y, wy, &jy0);
    int nx = resize_taps(x, wx, &jx0);
    for (int c = threadIdx.x; c < 512; c += 256){
        float acc = 0.f;
        for (int ty = 0; ty < ny; ++ty)
            for (int tx = 0; tx < nx; ++tx)
                acc += wy[ty]*wx[tx] *
                       pc18T[(size_t)(b*324 + (jy0+ty)*18 + (jx0+tx))*512 + c];
        pc_seq[(size_t)((y*16 + x)*4 + b)*512 + c] = acc;
    }
}

// pair LN at VSS entry: rows 0..2047, p=row>>10 picks (x,x2,weights[ibase+p])
__global__ __launch_bounds__(256) void ln_vss_pair_kernel(
    const float* __restrict__ x0, const float* __restrict__ x20,
    const float* __restrict__ x1, const float* __restrict__ x21,
    const float* __restrict__ wall, const float* __restrict__ ball,
    int ibase, bfloat* __restrict__ outb)
{
    int row = blockIdx.x*4 + (threadIdx.x >> 6);
    int lane = threadIdx.x & 63;
    int p = row >> 10, r2 = row & 1023;
    const float* in0 = (p ? x1 : x0) + (size_t)r2*512;
    const float* in1 = p ? x21 : x20;
    const float* w = wall + (ibase+p)*512;
    const float* b = ball + (ibase+p)*512;
    int base = lane*8;
    float v[8];
    #pragma unroll
    for (int t = 0; t < 8; ++t){
        v[t] = in0[base + t];
        if (in1) v[t] += in1[(size_t)r2*512 + base + t];
    }
    float mean, rstd;
    ln_stats(v, mean, rstd);
    bfloat* o = outb + (size_t)p*SEQ + (size_t)r2*512 + base;
    union { ushort u[8]; uint4 q; } pk;
    #pragma unroll
    for (int t = 0; t < 8; ++t)
        pk.u[t] = bfbits((v[t] - mean)*rstd*w[base + t] + b[base + t]);
    *(uint4*)o = pk.q;
}

// tgt = LN(a0+a1; w1,b1) + LN(c0+c1; w2,b2); fp32 + bf16 out
__global__ __launch_bounds__(256) void dn_pair_kernel(
    const float* __restrict__ a0, const float* __restrict__ a1,
    const float* __restrict__ w1, const float* __restrict__ b1,
    const float* __restrict__ c0, const float* __restrict__ c1,
    const float* __restrict__ w2, const float* __restrict__ b2,
    float* __restrict__ outf, bfloat* __restrict__ outb)
{
    int row = blockIdx.x*4 + (threadIdx.x >> 6);
    int lane = threadIdx.x & 63;
    int base = lane*8;
    size_t ro = (size_t)row*512 + base;
    float va[8], vc[8];
    #pragma unroll
    for (int t = 0; t < 8; ++t){ va[t] = a0[ro+t] + a1[ro+t]; vc[t] = c0[ro+t] + c1[ro+t]; }
    float m1, r1, m2, r2;
    ln_stats(va, m1, r1);
    ln_stats(vc, m2, r2);
    union { ushort u[8]; uint4 q; } pk;
    #pragma unroll
    for (int t = 0; t < 8; ++t){
        float o = (va[t]-m1)*r1*w1[base+t] + b1[base+t]
                + (vc[t]-m2)*r2*w2[base+t] + b2[base+t];
        outf[ro + t] = o;
        pk.u[t] = bfbits(o);
    }
    *(uint4*)(outb + ro) = pk.q;
}

// double-LN: y = LN(LN(in0+in1; w1,b1); w2,b2)
__global__ __launch_bounds__(256) void ln2_kernel(
    const float* __restrict__ in0, const float* __restrict__ in1,
    const float* __restrict__ w1, const float* __restrict__ b1,
    const float* __restrict__ w2, const float* __restrict__ b2,
    float* __restrict__ out)
{
    int row = blockIdx.x*4 + (threadIdx.x >> 6);
    int lane = threadIdx.x & 63;
    int base = lane*8;
    size_t ro = (size_t)row*512 + base;
    float v[8];
    #pragma unroll
    for (int t = 0; t < 8; ++t) v[t] = in0[ro+t] + in1[ro+t];
    float mean, rstd;
    ln_stats(v, mean, rstd);
    #pragma unroll
    for (int t = 0; t < 8; ++t) v[t] = (v[t]-mean)*rstd*w1[base+t] + b1[base+t];
    ln_stats(v, mean, rstd);
    #pragma unroll
    for (int t = 0; t < 8; ++t)
        out[ro + t] = (v[t]-mean)*rstd*w2[base+t] + b2[base+t];
}

// ---------------- bf16 MFMA GEMM, multi-job (blockIdx.z) ----------------
struct GJob {
    const bfloat* A; const bfloat* W;
    const float* bias; const float* res1; const float* res2;
    float* Cf; bfloat* Cb;
    const float* cw; const float* cb;               // epi==2 conv
    float* v; float* vr; bfloat* vb; bfloat* vrb;   // epi==2 outputs
};

// epi: 0 plain, 1 gelu, 2 conv+gelu dual-write (M=1024,N=512), 3 xproj scatter (N=272)
__global__ __launch_bounds__(256) void gemm3_kernel(
    GJob J0, GJob J1, GJob J2, GJob J3,
    int M, int N, int K, int nbn, int epi)
{
    __shared__ __align__(16) char lds[32768];
    const int z = blockIdx.z;
    GJob j = (z==0) ? J0 : (z==1) ? J1 : (z==2) ? J2 : J3;

    // bijective XCD swizzle (m204)
    int nwg = gridDim.x;
    int orig = blockIdx.x;
    int q = nwg >> 3, r = nwg & 7;
    int xcd = orig & 7, off = orig >> 3;
    int wgid = (xcd < r ? xcd*(q+1) : r*(q+1) + (xcd-r)*q) + off;
    int bm = (wgid / nbn) * 64;
    int bn = (wgid % nbn) * 64;

    const int tid = threadIdx.x;
    const int wv = tid >> 6, ln = tid & 63;

    const int r0 = tid >> 3;
    const int cs = (tid & 7) ^ (r0 & 7);
    int ar0 = bm + r0;       if (ar0 > M-1) ar0 = M-1;
    int ar1 = bm + r0 + 32;  if (ar1 > M-1) ar1 = M-1;
    int br0 = bn + r0;       if (br0 > N-1) br0 = N-1;
    int br1 = bn + r0 + 32;  if (br1 > N-1) br1 = N-1;
    const bfloat* a0p = j.A + (size_t)ar0*K + cs*8;
    const bfloat* a1p = j.A + (size_t)ar1*K + cs*8;
    const bfloat* b0p = j.W + (size_t)br0*K + cs*8;
    const bfloat* b1p = j.W + (size_t)br1*K + cs*8;

    auto STAGE = [&](int bb, int k0){
        char* base = lds + bb*16384 + wv*1024;
        glds16(a0p + k0, base);
        glds16(a1p + k0, base + 4096);
        glds16(b0p + k0, base + 8192);
        glds16(b1p + k0, base + 12288);
    };

    const int wr = wv >> 1, wc = wv & 1;
    const int fr = ln & 15, fc = ln >> 4;
    f32x4 acc[2][2] = {};

    auto COMP = [&](int bb){
        char* bA = lds + bb*16384;
        char* bB = bA + 8192;
        int ra0 = wr*32 + fr, ra1 = ra0 + 16;
        int rb0 = wc*32 + fr, rb1 = rb0 + 16;
        #pragma unroll
        for (int kk = 0; kk < 2; ++kk){
            int ch = kk*4 + fc;
            bfx8 a0 = *(const bfx8*)(bA + ra0*128 + ((ch ^ (ra0&7))<<4));
            bfx8 a1 = *(const bfx8*)(bA + ra1*128 + ((ch ^ (ra1&7))<<4));
            bfx8 b0 = *(const bfx8*)(bB + rb0*128 + ((ch ^ (rb0&7))<<4));
            bfx8 b1 = *(const bfx8*)(bB + rb1*128 + ((ch ^ (rb1&7))<<4));
            acc[0][0] = __builtin_amdgcn_mfma_f32_16x16x32_bf16(a0,b0,acc[0][0],0,0,0);
            acc[0][1] = __builtin_amdgcn_mfma_f32_16x16x32_bf16(a0,b1,acc[0][1],0,0,0);
            acc[1][0] = __builtin_amdgcn_mfma_f32_16x16x32_bf16(a1,b0,acc[1][0],0,0,0);
            acc[1][1] = __builtin_amdgcn_mfma_f32_16x16x32_bf16(a1,b1,acc[1][1],0,0,0);
        }
    };

    STAGE(0, 0);
    __syncthreads();
    const int nt = K >> 6;
    for (int t = 0; t < nt; ++t){
        int cur = t & 1;
        if (t + 1 < nt) STAGE(cur ^ 1, (t+1) << 6);
        COMP(cur);
        __syncthreads();
    }

    const int er = (ln >> 4) * 4;
    const int ec = ln & 15;

    if (epi == 2){
        // u = acc+bias -> LDS, depthwise conv along l (tile-local), gelu, dual write.
        float* ut = (float*)lds;
        #pragma unroll
        for (int i = 0; i < 2; ++i)
        #pragma unroll
        for (int jj = 0; jj < 2; ++jj)
        #pragma unroll
        for (int rr = 0; rr < 4; ++rr){
            int ml = wr*32 + i*16 + er + rr;
            int nl = wc*32 + jj*16 + ec;
            ut[ml*65 + nl] = acc[i][jj][rr] + j.bias[bn + nl];
        }
        __syncthreads();
        int rrow = tid >> 2, c0 = (tid & 3) * 16;
        int bt4 = rrow & ~3, lv = rrow & 3;
        int m = bm + rrow;
        int mrev = bm + bt4 + 3 - lv;
        float g[16];
        #pragma unroll
        for (int c = 0; c < 16; ++c){
            int n = bn + c0 + c;
            float a = j.cb[n];
            #pragma unroll
            for (int kh = 0; kh < 3; ++kh){
                int hh = lv + kh - 1;
                if (hh >= 0 && hh < 4)
                    a += ut[(bt4 + hh)*65 + c0 + c] * j.cw[(n*3 + kh)*3 + 1];
            }
            g[c] = gelu_tanh(a);
        }
        #pragma unroll
        for (int c = 0; c < 16; c += 4){
            float4 f = make_float4(g[c], g[c+1], g[c+2], g[c+3]);
            *(float4*)(j.v + (size_t)m*512 + bn + c0 + c) = f;
        }
        union { ushort u[8]; uint4 qv; } pk;
        #pragma unroll
        for (int h = 0; h < 2; ++h){
            #pragma unroll
            for (int t = 0; t < 8; ++t) pk.u[t] = bfbits(g[h*8 + t]);
            *(uint4*)(j.vb  + (size_t)m   *512 + bn + c0 + h*8) = pk.qv;
            *(uint4*)(j.vrb + (size_t)mrev*512 + bn + c0 + h*8) = pk.qv;
        }
        return;
    }

    #pragma unroll
    for (int i = 0; i < 2; ++i)
    #pragma unroll
    for (int jj = 0; jj < 2; ++jj)
    #pragma unroll
    for (int rr = 0; rr < 4; ++rr){
        int m = bm + wr*32 + i*16 + er + rr;
        int n = bn + wc*32 + jj*16 + ec;
        if (m >= M || n >= N) continue;
        float v = acc[i][jj][rr];
        if (j.bias) v += j.bias[n];
        if (epi == 1) v = gelu_tanh(v);
        if (j.res1) v += j.res1[(size_t)m*N + n];
        if (j.res2) v += j.res2[(size_t)m*N + n];
        if (epi == 3){
            int k2 = n >= 136;
            int cc = n - (k2 ? 136 : 0);
            j.Cf[((size_t)(k2*1024 + m))*136 + cc] = v;
        } else {
            if (j.Cf) j.Cf[(size_t)m*N + n] = v;
            if (j.Cb) j.Cb[(size_t)m*N + n] = __float2bfloat16(v);
        }
    }
}

// ---------------- fused selective scan + combine + LN ----------------
// L=4 closed form: y_l[d] = D*x_l[d] + sum_{l'<=l} w(l,l')*dt_{l'}*S[l][l']*x_{l'}[d]
// with S[l][l'] = B_{l'}.C_l (shared across the 8 nh heads of a (bt,k)).
// Block = one (p,bt); wave k = direction k; combine+LN by wave l.
__global__ __launch_bounds__(256) void scan_fused_kernel(
    const float* __restrict__ xdbl,   // [2][4][1024][136]
    const float* __restrict__ v,      // [2][1024][512]  (fwd layout only)
    const float* __restrict__ dt_bias,// + ibase*32 pre-offset
    const float* __restrict__ A_log,
    const float* __restrict__ Dp,
    const float* __restrict__ von_w, const float* __restrict__ von_b,
    int ibase, bfloat* __restrict__ outb)
{
    __shared__ float yb[4][4][512];   // [k][l][d] 32KB
    int blk = blockIdx.x;
    int p = blk >> 8, bt = blk & 255;
    int k = threadIdx.x >> 6, lane = threadIdx.x & 63;

    const float* xd = xdbl + (size_t)p*XDBL_P + (size_t)(k*1024 + bt*4)*136;

    // B,C rows (lane = n)
    float bb[4], cc[4];
    #pragma unroll
    for (int l = 0; l < 4; ++l){
        bb[l] = xd[l*136 + 8 + lane];
        cc[l] = xd[l*136 + 72 + lane];
    }

    // dt/dA: lane slot (l*8+nh) for lane&31
    int sl = (lane & 31) >> 3, snh = lane & 7;
    float Aval = -expf(A_log[p*32 + k*8 + snh]);
    float draw = xd[sl*136 + snh] + dt_bias[p*32 + k*8 + snh];
    float dtv = fmaxf(draw, 0.f) + log1pf(expf(-fabsf(draw)));
    float dAv = expf(dtv * Aval);

    // S[l][l'] = sum_n C_l[n]*B_l'[n] : 16 batched wave reductions
    float s[16];
    #pragma unroll
    for (int l = 0; l < 4; ++l)
    #pragma unroll
    for (int j = 0; j < 4; ++j)
        s[l*4+j] = cc[l]*bb[j];
    #pragma unroll
    for (int off = 32; off > 0; off >>= 1)
        #pragma unroll
        for (int i = 0; i < 16; ++i)
            s[i] += __shfl_xor(s[i], off, 64);

    // x[l'][nh] for this lane's d2 = lane (within head nh)
    float x[4][8];
    #pragma unroll
    for (int lp = 0; lp < 4; ++lp){
        int row = bt*4 + ((k < 2) ? lp : 3 - lp);
        const float* xr = v + (size_t)p*SEQ + (size_t)row*512 + lane;
        #pragma unroll
        for (int nh = 0; nh < 8; ++nh) x[lp][nh] = xr[nh*64];
    }

    #pragma unroll
    for (int nh = 0; nh < 8; ++nh){
        float dtl[4], dal[4];
        #pragma unroll
        for (int l = 0; l < 4; ++l){
            dtl[l] = __shfl(dtv, l*8 + nh, 64);
            dal[l] = __shfl(dAv, l*8 + nh, 64);
        }
        float Dv = Dp[p*32 + k*8 + nh];
        float coef[4] = {0.f, 0.f, 0.f, 0.f};
        #pragma unroll
        for (int l = 0; l < 4; ++l){
            #pragma unroll
            for (int j = 0; j < 4; ++j) coef[j] *= dal[l];
            coef[l] = dtl[l];
            float y = Dv * x[l][nh];
            #pragma unroll
            for (int j = 0; j <= l; ++j) y += coef[j]*s[l*4+j]*x[j][nh];
            yb[k][l][nh*64 + lane] = y;
        }
    }
    __syncthreads();

    // combine + LN: wave k acts as row l
    int l = k, rl = 3 - k;
    int base = lane*8;
    float vv[8];
    #pragma unroll
    for (int t = 0; t < 8; ++t)
        vv[t] = yb[0][l][base+t] + yb[1][l][base+t]
              + yb[2][rl][base+t] + yb[3][rl][base+t];
    float mean, rstd;
    ln_stats(vv, mean, rstd);
    const float* w = von_w + (ibase+p)*512;
    const float* bv = von_b + (ibase+p)*512;
    union { ushort u[8]; uint4 qv; } pk;
    #pragma unroll
    for (int t = 0; t < 8; ++t)
        pk.u[t] = bfbits((vv[t]-mean)*rstd*w[base+t] + bv[base+t]);
    *(uint4*)(outb + (size_t)p*SEQ + (size_t)(bt*4 + l)*512 + base) = pk.qv;
}

extern "C" void kernel_launch(void* const* d_in, const int* in_sizes, int n_in,
                              void* d_out, int out_size, void* d_ws, size_t ws_size,
                              hipStream_t stream)
{
    const float* style   = (const float*)d_in[0];
    const float* content = (const float*)d_in[2];
    const float* pos_s   = (const float*)d_in[4];
    const float* newps_w = (const float*)d_in[5];
    const float* newps_b = (const float*)d_in[6];
    const float* vln_w   = (const float*)d_in[7];
    const float* vln_b   = (const float*)d_in[8];
    const float* vin_b   = (const float*)d_in[10];
    const float* vconv_w = (const float*)d_in[11];
    const float* vconv_b = (const float*)d_in[12];
    const float* vdt_bias= (const float*)d_in[14];
    const float* vA_log  = (const float*)d_in[15];
    const float* vD      = (const float*)d_in[16];
    const float* von_w   = (const float*)d_in[17];
    const float* von_b   = (const float*)d_in[18];
    const float* vout_b  = (const float*)d_in[20];
    const float* lin1_b  = (const float*)d_in[22];
    const float* lin2_b  = (const float*)d_in[24];
    const float* dn1_w   = (const float*)d_in[25];
    const float* dn1_b   = (const float*)d_in[26];
    const float* dn2_w   = (const float*)d_in[27];
    const float* dn2_b   = (const float*)d_in[28];
    const float* dn3_w   = (const float*)d_in[29];
    const float* dn3_b   = (const float*)d_in[30];
    const float* decn_w  = (const float*)d_in[31];
    const float* decn_b  = (const float*)d_in[32];

    float* out = (float*)d_out;
    float* ws  = (float*)d_ws;

    // ---- fp32 region ----
    float* s_seq  = ws + (size_t) 0*SEQ;
    float* c_seq  = ws + (size_t) 1*SEQ;
    float* ps_seq = ws + (size_t) 2*SEQ;
    float* pc_seq = ws + (size_t) 3*SEQ;
    float* s_enc  = ws + (size_t) 4*SEQ;
    float* c_enc  = ws + (size_t) 5*SEQ;
    float* t1     = ws + (size_t) 6*SEQ;
    float* t2     = ws + (size_t) 7*SEQ;
    float* tgt    = ws + (size_t) 8*SEQ;
    float* ffnout = ws + (size_t) 9*SEQ;
    float* vbuf   = ws + (size_t)10*SEQ;   // [2][SEQ]
    float* xdbl   = ws + (size_t)12*SEQ;   // [2][557056] spans 12-14
    float* pc18T  = ws + (size_t)15*SEQ;   // pre-VSS only (663552)
    float* tgt3   = vbuf;                  // post-FFN only

    // ---- bf16 region at 17 SEQ floats ----
    bfloat* wb = (bfloat*)(ws + (size_t)17*SEQ);
    bfloat* wb_vin    = wb;                         // 4*512*512
    bfloat* wb_xproj  = wb + 1048576;               // 4*4*136*512
    bfloat* wb_vout   = wb + 2162688;
    bfloat* wb_lin1   = wb + 3211264;
    bfloat* wb_lin2   = wb + 4259840;
    bfloat* wb_newps  = wb + 5308416;
    bfloat* xn_bf     = wb + 5570560;               // [2][SEQ] (also yln pair)
    bfloat* vbuf_bf   = xn_bf   + (size_t)2*SEQ;    // [2][SEQ]
    bfloat* vrev_bf   = vbuf_bf + (size_t)2*SEQ;    // [2][SEQ]
    bfloat* tgt_bf    = vrev_bf + (size_t)2*SEQ;    // SEQ
    bfloat* ffn_bf    = tgt_bf  + (size_t)SEQ;      // 1024*2048
    bfloat* pooled_bf = ffn_bf;                     // pre-VSS only

    auto launch_gemm = [&](GJob* jobs, int nz, int M, int N, int K, int epi){
        int nbm = (M + 63)/64, nbn = (N + 63)/64;
        dim3 g(nbm*nbn, 1, nz);
        gemm3_kernel<<<g, 256, 0, stream>>>(jobs[0], jobs[nz>1?1:0],
                                            jobs[nz>2?2:0], jobs[nz>3?3:0],
                                            M, N, K, nbn, epi);
    };

    GJob Z = {};

    auto vss_pair = [&](const float* xa, const float* x2a,
                        const float* xb, const float* x2b,
                        int ibase, float* oa, float* ob){
        ln_vss_pair_kernel<<<512, 256, 0, stream>>>(xa, x2a, xb, x2b,
                                                    vln_w, vln_b, ibase, xn_bf);
        GJob jv[2];
        for (int p = 0; p < 2; ++p){
            int i = ibase + p;
            jv[p] = Z;
            jv[p].A = xn_bf + (size_t)p*SEQ;
            jv[p].W = wb_vin + (size_t)i*262144;
            jv[p].bias = vin_b + i*512;
            jv[p].cw = vconv_w + (size_t)i*4608;
            jv[p].cb = vconv_b + i*512;
            jv[p].v   = vbuf + (size_t)p*SEQ;
            jv[p].vb  = vbuf_bf + (size_t)p*SEQ;
            jv[p].vrb = vrev_bf + (size_t)p*SEQ;
        }
        launch_gemm(jv, 2, MROWS, 512, 512, 2);

        GJob jx[4];
        for (int zz = 0; zz < 4; ++zz){
            int p = zz >> 1, rev = zz & 1, i = ibase + p;
            jx[zz] = Z;
            jx[zz].A = (rev ? vrev_bf : vbuf_bf) + (size_t)p*SEQ;
            jx[zz].W = wb_xproj + (size_t)i*278528 + (size_t)rev*272*512;
            jx[zz].Cf = xdbl + (size_t)p*XDBL_P + (size_t)rev*278528;
        }
        launch_gemm(jx, 4, MROWS, 272, 512, 3);

        scan_fused_kernel<<<512, 256, 0, stream>>>(xdbl, vbuf,
                                                   vdt_bias + ibase*32,
                                                   vA_log + ibase*32,
                                                   vD + ibase*32,
                                                   von_w, von_b, ibase, xn_bf);

        GJob jo[2];
        const float* r1[2] = {xa, xb};
        const float* r2[2] = {x2a, x2b};
        float* oo[2] = {oa, ob};
        for (int p = 0; p < 2; ++p){
            int i = ibase + p;
            jo[p] = Z;
            jo[p].A = xn_bf + (size_t)p*SEQ;
            jo[p].W = wb_vout + (size_t)i*262144;
            jo[p].bias = vout_b + i*512;
            jo[p].res1 = r1[p];
            jo[p].res2 = r2[p];
            jo[p].Cf = oo[p];
        }
        launch_gemm(jo, 2, MROWS, 512, 512, 0);
    };

    // ---- weight conversion ----
    CvtArgs ca;
    ca.s[0]=(const float*)d_in[9];  ca.d[0]=wb_vin;
    ca.s[1]=(const float*)d_in[13]; ca.d[1]=wb_xproj;
    ca.s[2]=(const float*)d_in[19]; ca.d[2]=wb_vout;
    ca.s[3]=(const float*)d_in[21]; ca.d[3]=wb_lin1;
    ca.s[4]=(const float*)d_in[23]; ca.d[4]=wb_lin2;
    ca.s[5]=newps_w;                ca.d[5]=wb_newps;
    ca.c4[0]=262144; ca.c4[1]=540672; ca.c4[2]=802816;
    ca.c4[3]=1064960; ca.c4[4]=1327104; ca.c4[5]=1392640;
    cvt_w_kernel<<<(1392640+255)/256, 256, 0, stream>>>(ca, 1392640);

    // ---- positional path + layout ----
    to_seq3_kernel<<<1536, 256, 0, stream>>>(style, content, pos_s,
                                             s_seq, c_seq, ps_seq);
    pool_kernel<<<1296, 256, 0, stream>>>(content, pooled_bf);
    GJob jn = Z;
    jn.A = pooled_bf; jn.W = wb_newps; jn.bias = newps_b; jn.Cf = pc18T;
    launch_gemm(&jn, 1, 1296, 512, 512, 0);
    resize_kernel<<<1024, 256, 0, stream>>>(pc18T, pc_seq);

    // ---- encoders (pair) ----
    vss_pair(s_seq, nullptr, c_seq, nullptr, 0, s_enc, c_enc);

    // ---- decoders (pair) ----
    vss_pair(c_enc, pc_seq, s_enc, ps_seq, 2, t1, t2);
    dn_pair_kernel<<<256, 256, 0, stream>>>(c_enc, t1, dn1_w, dn1_b,
                                            s_enc, t2, dn2_w, dn2_b,
                                            tgt, tgt_bf);

    // ---- FFN + tail ----
    GJob jf = Z;
    jf.A = tgt_bf; jf.W = wb_lin1; jf.bias = lin1_b; jf.Cb = ffn_bf;
    launch_gemm(&jf, 1, MROWS, 2048, 512, 1);
    GJob jg = Z;
    jg.A = ffn_bf; jg.W = wb_lin2; jg.bias = lin2_b; jg.Cf = ffnout;
    launch_gemm(&jg, 1, MROWS, 512, 2048, 0);
    ln2_kernel<<<256, 256, 0, stream>>>(tgt, ffnout, dn3_w, dn3_b,
                                        decn_w, decn_b, tgt3);
    from_seq_kernel<<<SEQ/256, 256, 0, stream>>>(tgt3, out);
}

// Round 6
// 171.900 us; speedup vs baseline: 6.6334x; 1.1078x over previous
//
#include <hip/hip_runtime.h>
#include <hip/hip_bf16.h>
#include <math.h>

// ---------------- problem constants ----------------
#define SEQ   524288          // 256*4*512 floats per sequence tensor
#define MROWS 1024            // 256*4 rows of 512
#define XDBL_P 557056         // 4*1024*136 per pair element

typedef __hip_bfloat16 bfloat;
typedef __bf16 bfx8 __attribute__((ext_vector_type(8)));
typedef float f32x4 __attribute__((ext_vector_type(4)));

// fast tanh-gelu via v_exp_f32 (jax.nn.gelu approximate=True)
__device__ __forceinline__ float gelu_tanh(float x){
    float x3 = x*x*x;
    float z = 0.7978845608028654f*(x + 0.044715f*x3);
    float az = fabsf(z);
    float e = __expf(-2.f*az);
    float th = copysignf((1.f - e)/(1.f + e), z);
    return 0.5f*x*(1.f + th);
}

__device__ __forceinline__ unsigned short bfbits(float x){
    union { __hip_bfloat16 h; unsigned short u; } cv;
    cv.h = __float2bfloat16(x);
    return cv.u;
}

__device__ __forceinline__ void glds16(const void* g, void* l){
    __builtin_amdgcn_global_load_lds(
        (const __attribute__((address_space(1))) unsigned int*)g,
        (__attribute__((address_space(3))) unsigned int*)l, 16, 0, 0);
}

#define VMWAIT(n) asm volatile("s_waitcnt vmcnt(" #n ")" ::: "memory")

// wave-level LN stats over v[8] (64 lanes * 8 = 512)
__device__ __forceinline__ void ln_stats(const float* v, float& mean, float& rstd){
    float s = 0.f;
    #pragma unroll
    for (int t = 0; t < 8; ++t) s += v[t];
    #pragma unroll
    for (int off = 32; off > 0; off >>= 1) s += __shfl_xor(s, off, 64);
    mean = s * (1.f/512.f);
    float sq = 0.f;
    #pragma unroll
    for (int t = 0; t < 8; ++t){ float d = v[t] - mean; sq += d*d; }
    #pragma unroll
    for (int off = 32; off > 0; off >>= 1) sq += __shfl_xor(sq, off, 64);
    rstd = rsqrtf(sq * (1.f/512.f) + 1e-5f);
}

// -------- weight fp32 -> bf16 conversion --------
struct CvtArgs {
    const float* s[6];
    bfloat* d[6];
    int c4[6];
};
__global__ void cvt_w_kernel(CvtArgs a, int total4){
    int i = blockIdx.x*256 + threadIdx.x;
    if (i >= total4) return;
    int j = 0, base = 0;
    while (j < 5 && i >= a.c4[j]) { base = a.c4[j]; ++j; }
    int k = i - base;
    float4 v = ((const float4*)a.s[j])[k];
    union { bfloat h[4]; ushort4 u; } o;
    o.h[0] = __float2bfloat16(v.x); o.h[1] = __float2bfloat16(v.y);
    o.h[2] = __float2bfloat16(v.z); o.h[3] = __float2bfloat16(v.w);
    *(ushort4*)(a.d[j] + (size_t)k*4) = o.u;
}

// LDS-tiled transpose: (b,c,l) -> seq[(l*4+b)*512+c], 3 tensors.
__global__ void to_seq3_kernel(const float* __restrict__ s, const float* __restrict__ c,
                               const float* __restrict__ p,
                               float* __restrict__ os, float* __restrict__ oc,
                               float* __restrict__ op){
    __shared__ float t[32][33];
    int blk = blockIdx.x;            // [3][4][16][8]
    int lt = blk & 7;  blk >>= 3;
    int ct = blk & 15; blk >>= 4;
    int b  = blk & 3;  blk >>= 2;
    const float* in = blk==0 ? s : (blk==1 ? c : p);
    float* o = blk==0 ? os : (blk==1 ? oc : op);
    int c0 = ct*32, l0 = lt*32;
    int lx = threadIdx.x & 31, g = threadIdx.x >> 5;
    #pragma unroll
    for (int q = 0; q < 4; ++q){
        int cy = g + q*8;
        t[cy][lx] = in[(size_t)(b*512 + c0+cy)*256 + l0 + lx];
    }
    __syncthreads();
    #pragma unroll
    for (int q = 0; q < 4; ++q){
        int ly = g + q*8;
        o[((size_t)(l0+ly)*4 + b)*512 + c0 + lx] = t[lx][ly];
    }
}

__global__ void from_seq_kernel(const float* __restrict__ in, float* __restrict__ out){
    int idx = blockIdx.x*256 + threadIdx.x;
    int l = idx & 255;
    int c = (idx >> 8) & 511;
    int b = idx >> 17;
    out[idx] = in[(size_t)(l*4 + b)*512 + c];
}

// adaptive pool 16x16 -> 18x18, bf16 transposed out
__global__ void pool_kernel(const float* __restrict__ content, bfloat* __restrict__ pooledT){
    int bij = blockIdx.x;
    int b = bij / 324;
    int ij = bij % 324;
    int i = ij / 18, j = ij % 18;
    int s0 = (i*16)/18,  e0 = ((i+1)*16 + 17)/18;
    int s1 = (j*16)/18,  e1 = ((j+1)*16 + 17)/18;
    float inv = 1.0f / (float)((e0-s0)*(e1-s1));
    for (int c = threadIdx.x; c < 512; c += 256){
        float acc = 0.f;
        for (int h = s0; h < e0; ++h)
            for (int w = s1; w < e1; ++w)
                acc += content[((b*512 + c)*16 + h)*16 + w];
        pooledT[(size_t)(b*324 + ij)*512 + c] = __float2bfloat16(acc * inv);
    }
}

__device__ __forceinline__ int resize_taps(int o, float* w, int* j0_out){
    const float inv_scale = 18.0f/16.0f;
    float sf = (o + 0.5f)*inv_scale - 0.5f;
    int j0 = (int)ceilf(sf - inv_scale);
    int j1 = (int)floorf(sf + inv_scale);
    if (j0 < 0) j0 = 0;
    if (j1 > 17) j1 = 17;
    int n = j1 - j0 + 1;
    float sum = 0.f;
    for (int t = 0; t < n; ++t){
        float d = fabsf(sf - (float)(j0 + t)) * (16.0f/18.0f);
        float v = fmaxf(0.f, 1.f - d);
        w[t] = v; sum += v;
    }
    float r = 1.f / sum;
    for (int t = 0; t < n; ++t) w[t] *= r;
    *j0_out = j0;
    return n;
}

__global__ void resize_kernel(const float* __restrict__ pc18T, float* __restrict__ pc_seq){
    int bid = blockIdx.x;
    int b = bid >> 8;
    int yx = bid & 255;
    int y = yx >> 4, x = yx & 15;
    float wy[3], wx[3];
    int jy0, jx0;
    int ny = resize_taps(y, wy, &jy0);
    int nx = resize_taps(x, wx, &jx0);
    for (int c = threadIdx.x; c < 512; c += 256){
        float acc = 0.f;
        for (int ty = 0; ty < ny; ++ty)
            for (int tx = 0; tx < nx; ++tx)
                acc += wy[ty]*wx[tx] *
                       pc18T[(size_t)(b*324 + (jy0+ty)*18 + (jx0+tx))*512 + c];
        pc_seq[(size_t)((y*16 + x)*4 + b)*512 + c] = acc;
    }
}

// pair LN at VSS entry: rows 0..2047, p=row>>10 picks (x,x2,weights[ibase+p])
__global__ __launch_bounds__(256) void ln_vss_pair_kernel(
    const float* __restrict__ x0, const float* __restrict__ x20,
    const float* __restrict__ x1, const float* __restrict__ x21,
    const float* __restrict__ wall, const float* __restrict__ ball,
    int ibase, bfloat* __restrict__ outb)
{
    int row = blockIdx.x*4 + (threadIdx.x >> 6);
    int lane = threadIdx.x & 63;
    int p = row >> 10, r2 = row & 1023;
    const float* in0 = (p ? x1 : x0) + (size_t)r2*512;
    const float* in1 = p ? x21 : x20;
    const float* w = wall + (ibase+p)*512;
    const float* b = ball + (ibase+p)*512;
    int base = lane*8;
    float v[8];
    #pragma unroll
    for (int t = 0; t < 8; ++t){
        v[t] = in0[base + t];
        if (in1) v[t] += in1[(size_t)r2*512 + base + t];
    }
    float mean, rstd;
    ln_stats(v, mean, rstd);
    bfloat* o = outb + (size_t)p*SEQ + (size_t)r2*512 + base;
    union { ushort u[8]; uint4 q; } pk;
    #pragma unroll
    for (int t = 0; t < 8; ++t)
        pk.u[t] = bfbits((v[t] - mean)*rstd*w[base + t] + b[base + t]);
    *(uint4*)o = pk.q;
}

// tgt = LN(a0+a1; w1,b1) + LN(c0+c1; w2,b2); fp32 + bf16 out
__global__ __launch_bounds__(256) void dn_pair_kernel(
    const float* __restrict__ a0, const float* __restrict__ a1,
    const float* __restrict__ w1, const float* __restrict__ b1,
    const float* __restrict__ c0, const float* __restrict__ c1,
    const float* __restrict__ w2, const float* __restrict__ b2,
    float* __restrict__ outf, bfloat* __restrict__ outb)
{
    int row = blockIdx.x*4 + (threadIdx.x >> 6);
    int lane = threadIdx.x & 63;
    int base = lane*8;
    size_t ro = (size_t)row*512 + base;
    float va[8], vc[8];
    #pragma unroll
    for (int t = 0; t < 8; ++t){ va[t] = a0[ro+t] + a1[ro+t]; vc[t] = c0[ro+t] + c1[ro+t]; }
    float m1, r1, m2, r2;
    ln_stats(va, m1, r1);
    ln_stats(vc, m2, r2);
    union { ushort u[8]; uint4 q; } pk;
    #pragma unroll
    for (int t = 0; t < 8; ++t){
        float o = (va[t]-m1)*r1*w1[base+t] + b1[base+t]
                + (vc[t]-m2)*r2*w2[base+t] + b2[base+t];
        outf[ro + t] = o;
        pk.u[t] = bfbits(o);
    }
    *(uint4*)(outb + ro) = pk.q;
}

// double-LN: y = LN(LN(in0+in1; w1,b1); w2,b2)
__global__ __launch_bounds__(256) void ln2_kernel(
    const float* __restrict__ in0, const float* __restrict__ in1,
    const float* __restrict__ w1, const float* __restrict__ b1,
    const float* __restrict__ w2, const float* __restrict__ b2,
    float* __restrict__ out)
{
    int row = blockIdx.x*4 + (threadIdx.x >> 6);
    int lane = threadIdx.x & 63;
    int base = lane*8;
    size_t ro = (size_t)row*512 + base;
    float v[8];
    #pragma unroll
    for (int t = 0; t < 8; ++t) v[t] = in0[ro+t] + in1[ro+t];
    float mean, rstd;
    ln_stats(v, mean, rstd);
    #pragma unroll
    for (int t = 0; t < 8; ++t) v[t] = (v[t]-mean)*rstd*w1[base+t] + b1[base+t];
    ln_stats(v, mean, rstd);
    #pragma unroll
    for (int t = 0; t < 8; ++t)
        out[ro + t] = (v[t]-mean)*rstd*w2[base+t] + b2[base+t];
}

// ---------------- bf16 MFMA GEMM, multi-job, counted-vmcnt pipeline ----------
struct GJob {
    const bfloat* A; const bfloat* W;
    const float* bias; const float* res1; const float* res2;
    float* Cf; bfloat* Cb;
    const float* cw; const float* cb;               // epi==2 conv
    float* v; float* vr; bfloat* vb; bfloat* vrb;   // epi==2 outputs
};

// epi: 0 plain, 1 gelu, 2 conv+gelu dual-write (M=1024,N=512), 3 xproj scatter (N=272)
// 4 LDS buffers x 16KB, 3-deep prefetch, s_waitcnt vmcnt(8) steady state,
// raw s_barrier (never drains the load queue in the main loop).
__global__ __launch_bounds__(256) void gemm3_kernel(
    GJob J0, GJob J1, GJob J2, GJob J3,
    int M, int N, int K, int nbn, int epi)
{
    __shared__ __align__(16) char lds[65536];
    const int z = blockIdx.z;
    GJob j = (z==0) ? J0 : (z==1) ? J1 : (z==2) ? J2 : J3;

    // bijective XCD swizzle (m204)
    int nwg = gridDim.x;
    int orig = blockIdx.x;
    int q = nwg >> 3, r = nwg & 7;
    int xcd = orig & 7, off = orig >> 3;
    int wgid = (xcd < r ? xcd*(q+1) : r*(q+1) + (xcd-r)*q) + off;
    int bm = (wgid / nbn) * 64;
    int bn = (wgid % nbn) * 64;

    const int tid = threadIdx.x;
    const int wv = tid >> 6, ln = tid & 63;

    const int r0 = tid >> 3;
    const int cs = (tid & 7) ^ (r0 & 7);
    int ar0 = bm + r0;       if (ar0 > M-1) ar0 = M-1;
    int ar1 = bm + r0 + 32;  if (ar1 > M-1) ar1 = M-1;
    int br0 = bn + r0;       if (br0 > N-1) br0 = N-1;
    int br1 = bn + r0 + 32;  if (br1 > N-1) br1 = N-1;
    const bfloat* a0p = j.A + (size_t)ar0*K + cs*8;
    const bfloat* a1p = j.A + (size_t)ar1*K + cs*8;
    const bfloat* b0p = j.W + (size_t)br0*K + cs*8;
    const bfloat* b1p = j.W + (size_t)br1*K + cs*8;

    auto STAGE = [&](int bb, int k0){
        char* base = lds + bb*16384 + wv*1024;
        glds16(a0p + k0, base);
        glds16(a1p + k0, base + 4096);
        glds16(b0p + k0, base + 8192);
        glds16(b1p + k0, base + 12288);
    };

    const int wr = wv >> 1, wc = wv & 1;
    const int fr = ln & 15, fc = ln >> 4;
    f32x4 acc[2][2] = {};

    auto COMP = [&](int bb){
        char* bA = lds + bb*16384;
        char* bB = bA + 8192;
        int ra0 = wr*32 + fr, ra1 = ra0 + 16;
        int rb0 = wc*32 + fr, rb1 = rb0 + 16;
        #pragma unroll
        for (int kk = 0; kk < 2; ++kk){
            int ch = kk*4 + fc;
            bfx8 a0 = *(const bfx8*)(bA + ra0*128 + ((ch ^ (ra0&7))<<4));
            bfx8 a1 = *(const bfx8*)(bA + ra1*128 + ((ch ^ (ra1&7))<<4));
            bfx8 b0 = *(const bfx8*)(bB + rb0*128 + ((ch ^ (rb0&7))<<4));
            bfx8 b1 = *(const bfx8*)(bB + rb1*128 + ((ch ^ (rb1&7))<<4));
            acc[0][0] = __builtin_amdgcn_mfma_f32_16x16x32_bf16(a0,b0,acc[0][0],0,0,0);
            acc[0][1] = __builtin_amdgcn_mfma_f32_16x16x32_bf16(a0,b1,acc[0][1],0,0,0);
            acc[1][0] = __builtin_amdgcn_mfma_f32_16x16x32_bf16(a1,b0,acc[1][0],0,0,0);
            acc[1][1] = __builtin_amdgcn_mfma_f32_16x16x32_bf16(a1,b1,acc[1][1],0,0,0);
        }
    };

    const int nt = K >> 6;
    // prologue: 3-deep prefetch
    for (int s = 0; s < 3 && s < nt; ++s) STAGE(s, s << 6);
    for (int t = 0; t < nt; ++t){
        int rem = nt - 1 - t;
        if (rem >= 2)      VMWAIT(8);   // stage t landed; t+1,t+2 in flight
        else if (rem == 1) VMWAIT(4);
        else               VMWAIT(0);
        __builtin_amdgcn_sched_barrier(0);
        __builtin_amdgcn_s_barrier();    // raw: does NOT drain the load queue
        if (t + 3 < nt) STAGE((t+3) & 3, (t+3) << 6);
        COMP(t & 3);
    }

    const int er = (ln >> 4) * 4;
    const int ec = ln & 15;

    if (epi == 2){
        // u = acc+bias -> LDS, depthwise conv along l (tile-local), gelu, dual write.
        __syncthreads();                 // all COMP reads retired before LDS reuse
        float* ut = (float*)lds;
        #pragma unroll
        for (int i = 0; i < 2; ++i)
        #pragma unroll
        for (int jj = 0; jj < 2; ++jj)
        #pragma unroll
        for (int rr = 0; rr < 4; ++rr){
            int ml = wr*32 + i*16 + er + rr;
            int nl = wc*32 + jj*16 + ec;
            ut[ml*65 + nl] = acc[i][jj][rr] + j.bias[bn + nl];
        }
        __syncthreads();
        int rrow = tid >> 2, c0 = (tid & 3) * 16;
        int bt4 = rrow & ~3, lv = rrow & 3;
        int m = bm + rrow;
        int mrev = bm + bt4 + 3 - lv;
        float g[16];
        #pragma unroll
        for (int c = 0; c < 16; ++c){
            int n = bn + c0 + c;
            float a = j.cb[n];
            #pragma unroll
            for (int kh = 0; kh < 3; ++kh){
                int hh = lv + kh - 1;
                if (hh >= 0 && hh < 4)
                    a += ut[(bt4 + hh)*65 + c0 + c] * j.cw[(n*3 + kh)*3 + 1];
            }
            g[c] = gelu_tanh(a);
        }
        #pragma unroll
        for (int c = 0; c < 16; c += 4){
            float4 f = make_float4(g[c], g[c+1], g[c+2], g[c+3]);
            *(float4*)(j.v + (size_t)m*512 + bn + c0 + c) = f;
        }
        union { ushort u[8]; uint4 qv; } pk;
        #pragma unroll
        for (int h = 0; h < 2; ++h){
            #pragma unroll
            for (int t = 0; t < 8; ++t) pk.u[t] = bfbits(g[h*8 + t]);
            *(uint4*)(j.vb  + (size_t)m   *512 + bn + c0 + h*8) = pk.qv;
            *(uint4*)(j.vrb + (size_t)mrev*512 + bn + c0 + h*8) = pk.qv;
        }
        return;
    }

    #pragma unroll
    for (int i = 0; i < 2; ++i)
    #pragma unroll
    for (int jj = 0; jj < 2; ++jj)
    #pragma unroll
    for (int rr = 0; rr < 4; ++rr){
        int m = bm + wr*32 + i*16 + er + rr;
        int n = bn + wc*32 + jj*16 + ec;
        if (m >= M || n >= N) continue;
        float v = acc[i][jj][rr];
        if (j.bias) v += j.bias[n];
        if (epi == 1) v = gelu_tanh(v);
        if (j.res1) v += j.res1[(size_t)m*N + n];
        if (j.res2) v += j.res2[(size_t)m*N + n];
        if (epi == 3){
            int k2 = n >= 136;
            int cc = n - (k2 ? 136 : 0);
            j.Cf[((size_t)(k2*1024 + m))*136 + cc] = v;
        } else {
            if (j.Cf) j.Cf[(size_t)m*N + n] = v;
            if (j.Cb) j.Cb[(size_t)m*N + n] = __float2bfloat16(v);
        }
    }
}

// ---------------- fused selective scan + combine + LN ----------------
// L=4 closed form: y_l[d] = D*x_l[d] + sum_{l'<=l} w(l,l')*dt_{l'}*S[l][l']*x_{l'}[d]
// with S[l][l'] = B_{l'}.C_l (shared across the 8 nh heads of a (bt,k)).
__global__ __launch_bounds__(256) void scan_fused_kernel(
    const float* __restrict__ xdbl,   // [2][4][1024][136]
    const float* __restrict__ v,      // [2][1024][512]  (fwd layout only)
    const float* __restrict__ dt_bias,// + ibase*32 pre-offset
    const float* __restrict__ A_log,
    const float* __restrict__ Dp,
    const float* __restrict__ von_w, const float* __restrict__ von_b,
    int ibase, bfloat* __restrict__ outb)
{
    __shared__ float yb[4][4][512];   // [k][l][d] 32KB
    int blk = blockIdx.x;
    int p = blk >> 8, bt = blk & 255;
    int k = threadIdx.x >> 6, lane = threadIdx.x & 63;

    const float* xd = xdbl + (size_t)p*XDBL_P + (size_t)(k*1024 + bt*4)*136;

    float bb[4], cc[4];
    #pragma unroll
    for (int l = 0; l < 4; ++l){
        bb[l] = xd[l*136 + 8 + lane];
        cc[l] = xd[l*136 + 72 + lane];
    }

    int sl = (lane & 31) >> 3, snh = lane & 7;
    float Aval = -expf(A_log[p*32 + k*8 + snh]);
    float draw = xd[sl*136 + snh] + dt_bias[p*32 + k*8 + snh];
    float dtv = fmaxf(draw, 0.f) + log1pf(expf(-fabsf(draw)));
    float dAv = expf(dtv * Aval);

    float s[16];
    #pragma unroll
    for (int l = 0; l < 4; ++l)
    #pragma unroll
    for (int jj = 0; jj < 4; ++jj)
        s[l*4+jj] = cc[l]*bb[jj];
    #pragma unroll
    for (int off = 32; off > 0; off >>= 1)
        #pragma unroll
        for (int i = 0; i < 16; ++i)
            s[i] += __shfl_xor(s[i], off, 64);

    float x[4][8];
    #pragma unroll
    for (int lp = 0; lp < 4; ++lp){
        int row = bt*4 + ((k < 2) ? lp : 3 - lp);
        const float* xr = v + (size_t)p*SEQ + (size_t)row*512 + lane;
        #pragma unroll
        for (int nh = 0; nh < 8; ++nh) x[lp][nh] = xr[nh*64];
    }

    #pragma unroll
    for (int nh = 0; nh < 8; ++nh){
        float dtl[4], dal[4];
        #pragma unroll
        for (int l = 0; l < 4; ++l){
            dtl[l] = __shfl(dtv, l*8 + nh, 64);
            dal[l] = __shfl(dAv, l*8 + nh, 64);
        }
        float Dv = Dp[p*32 + k*8 + nh];
        float coef[4] = {0.f, 0.f, 0.f, 0.f};
        #pragma unroll
        for (int l = 0; l < 4; ++l){
            #pragma unroll
            for (int jj = 0; jj < 4; ++jj) coef[jj] *= dal[l];
            coef[l] = dtl[l];
            float y = Dv * x[l][nh];
            #pragma unroll
            for (int jj = 0; jj <= l; ++jj) y += coef[jj]*s[l*4+jj]*x[jj][nh];
            yb[k][l][nh*64 + lane] = y;
        }
    }
    __syncthreads();

    int l = k, rl = 3 - k;
    int base = lane*8;
    float vv[8];
    #pragma unroll
    for (int t = 0; t < 8; ++t)
        vv[t] = yb[0][l][base+t] + yb[1][l][base+t]
              + yb[2][rl][base+t] + yb[3][rl][base+t];
    float mean, rstd;
    ln_stats(vv, mean, rstd);
    const float* w = von_w + (ibase+p)*512;
    const float* bv = von_b + (ibase+p)*512;
    union { ushort u[8]; uint4 qv; } pk;
    #pragma unroll
    for (int t = 0; t < 8; ++t)
        pk.u[t] = bfbits((vv[t]-mean)*rstd*w[base+t] + bv[base+t]);
    *(uint4*)(outb + (size_t)p*SEQ + (size_t)(bt*4 + l)*512 + base) = pk.qv;
}

extern "C" void kernel_launch(void* const* d_in, const int* in_sizes, int n_in,
                              void* d_out, int out_size, void* d_ws, size_t ws_size,
                              hipStream_t stream)
{
    const float* style   = (const float*)d_in[0];
    const float* content = (const float*)d_in[2];
    const float* pos_s   = (const float*)d_in[4];
    const float* newps_w = (const float*)d_in[5];
    const float* newps_b = (const float*)d_in[6];
    const float* vln_w   = (const float*)d_in[7];
    const float* vln_b   = (const float*)d_in[8];
    const float* vin_b   = (const float*)d_in[10];
    const float* vconv_w = (const float*)d_in[11];
    const float* vconv_b = (const float*)d_in[12];
    const float* vdt_bias= (const float*)d_in[14];
    const float* vA_log  = (const float*)d_in[15];
    const float* vD      = (const float*)d_in[16];
    const float* von_w   = (const float*)d_in[17];
    const float* von_b   = (const float*)d_in[18];
    const float* vout_b  = (const float*)d_in[20];
    const float* lin1_b  = (const float*)d_in[22];
    const float* lin2_b  = (const float*)d_in[24];
    const float* dn1_w   = (const float*)d_in[25];
    const float* dn1_b   = (const float*)d_in[26];
    const float* dn2_w   = (const float*)d_in[27];
    const float* dn2_b   = (const float*)d_in[28];
    const float* dn3_w   = (const float*)d_in[29];
    const float* dn3_b   = (const float*)d_in[30];
    const float* decn_w  = (const float*)d_in[31];
    const float* decn_b  = (const float*)d_in[32];

    float* out = (float*)d_out;
    float* ws  = (float*)d_ws;

    // ---- fp32 region ----
    float* s_seq  = ws + (size_t) 0*SEQ;
    float* c_seq  = ws + (size_t) 1*SEQ;
    float* ps_seq = ws + (size_t) 2*SEQ;
    float* pc_seq = ws + (size_t) 3*SEQ;
    float* s_enc  = ws + (size_t) 4*SEQ;
    float* c_enc  = ws + (size_t) 5*SEQ;
    float* t1     = ws + (size_t) 6*SEQ;
    float* t2     = ws + (size_t) 7*SEQ;
    float* tgt    = ws + (size_t) 8*SEQ;
    float* ffnout = ws + (size_t) 9*SEQ;
    float* vbuf   = ws + (size_t)10*SEQ;   // [2][SEQ]
    float* xdbl   = ws + (size_t)12*SEQ;   // [2][557056] spans 12-14
    float* pc18T  = ws + (size_t)15*SEQ;   // pre-VSS only (663552)
    float* tgt3   = vbuf;                  // post-FFN only

    // ---- bf16 region at 17 SEQ floats ----
    bfloat* wb = (bfloat*)(ws + (size_t)17*SEQ);
    bfloat* wb_vin    = wb;                         // 4*512*512
    bfloat* wb_xproj  = wb + 1048576;               // 4*4*136*512
    bfloat* wb_vout   = wb + 2162688;
    bfloat* wb_lin1   = wb + 3211264;
    bfloat* wb_lin2   = wb + 4259840;
    bfloat* wb_newps  = wb + 5308416;
    bfloat* xn_bf     = wb + 5570560;               // [2][SEQ] (also yln pair)
    bfloat* vbuf_bf   = xn_bf   + (size_t)2*SEQ;    // [2][SEQ]
    bfloat* vrev_bf   = vbuf_bf + (size_t)2*SEQ;    // [2][SEQ]
    bfloat* tgt_bf    = vrev_bf + (size_t)2*SEQ;    // SEQ
    bfloat* ffn_bf    = tgt_bf  + (size_t)SEQ;      // 1024*2048
    bfloat* pooled_bf = ffn_bf;                     // pre-VSS only

    auto launch_gemm = [&](GJob* jobs, int nz, int M, int N, int K, int epi){
        int nbm = (M + 63)/64, nbn = (N + 63)/64;
        dim3 g(nbm*nbn, 1, nz);
        gemm3_kernel<<<g, 256, 0, stream>>>(jobs[0], jobs[nz>1?1:0],
                                            jobs[nz>2?2:0], jobs[nz>3?3:0],
                                            M, N, K, nbn, epi);
    };

    GJob Z = {};

    auto vss_pair = [&](const float* xa, const float* x2a,
                        const float* xb, const float* x2b,
                        int ibase, float* oa, float* ob){
        ln_vss_pair_kernel<<<512, 256, 0, stream>>>(xa, x2a, xb, x2b,
                                                    vln_w, vln_b, ibase, xn_bf);
        GJob jv[2];
        for (int p = 0; p < 2; ++p){
            int i = ibase + p;
            jv[p] = Z;
            jv[p].A = xn_bf + (size_t)p*SEQ;
            jv[p].W = wb_vin + (size_t)i*262144;
            jv[p].bias = vin_b + i*512;
            jv[p].cw = vconv_w + (size_t)i*4608;
            jv[p].cb = vconv_b + i*512;
            jv[p].v   = vbuf + (size_t)p*SEQ;
            jv[p].vb  = vbuf_bf + (size_t)p*SEQ;
            jv[p].vrb = vrev_bf + (size_t)p*SEQ;
        }
        launch_gemm(jv, 2, MROWS, 512, 512, 2);

        GJob jx[4];
        for (int zz = 0; zz < 4; ++zz){
            int p = zz >> 1, rev = zz & 1, i = ibase + p;
            jx[zz] = Z;
            jx[zz].A = (rev ? vrev_bf : vbuf_bf) + (size_t)p*SEQ;
            jx[zz].W = wb_xproj + (size_t)i*278528 + (size_t)rev*272*512;
            jx[zz].Cf = xdbl + (size_t)p*XDBL_P + (size_t)rev*278528;
        }
        launch_gemm(jx, 4, MROWS, 272, 512, 3);

        scan_fused_kernel<<<512, 256, 0, stream>>>(xdbl, vbuf,
                                                   vdt_bias + ibase*32,
                                                   vA_log + ibase*32,
                                                   vD + ibase*32,
                                                   von_w, von_b, ibase, xn_bf);

        GJob jo[2];
        const float* r1[2] = {xa, xb};
        const float* r2[2] = {x2a, x2b};
        float* oo[2] = {oa, ob};
        for (int p = 0; p < 2; ++p){
            int i = ibase + p;
            jo[p] = Z;
            jo[p].A = xn_bf + (size_t)p*SEQ;
            jo[p].W = wb_vout + (size_t)i*262144;
            jo[p].bias = vout_b + i*512;
            jo[p].res1 = r1[p];
            jo[p].res2 = r2[p];
            jo[p].Cf = oo[p];
        }
        launch_gemm(jo, 2, MROWS, 512, 512, 0);
    };

    // ---- weight conversion ----
    CvtArgs ca;
    ca.s[0]=(const float*)d_in[9];  ca.d[0]=wb_vin;
    ca.s[1]=(const float*)d_in[13]; ca.d[1]=wb_xproj;
    ca.s[2]=(const float*)d_in[19]; ca.d[2]=wb_vout;
    ca.s[3]=(const float*)d_in[21]; ca.d[3]=wb_lin1;
    ca.s[4]=(const float*)d_in[23]; ca.d[4]=wb_lin2;
    ca.s[5]=newps_w;                ca.d[5]=wb_newps;
    ca.c4[0]=262144; ca.c4[1]=540672; ca.c4[2]=802816;
    ca.c4[3]=1064960; ca.c4[4]=1327104; ca.c4[5]=1392640;
    cvt_w_kernel<<<(1392640+255)/256, 256, 0, stream>>>(ca, 1392640);

    // ---- positional path + layout ----
    to_seq3_kernel<<<1536, 256, 0, stream>>>(style, content, pos_s,
                                             s_seq, c_seq, ps_seq);
    pool_kernel<<<1296, 256, 0, stream>>>(content, pooled_bf);
    GJob jn = Z;
    jn.A = pooled_bf; jn.W = wb_newps; jn.bias = newps_b; jn.Cf = pc18T;
    launch_gemm(&jn, 1, 1296, 512, 512, 0);
    resize_kernel<<<1024, 256, 0, stream>>>(pc18T, pc_seq);

    // ---- encoders (pair) ----
    vss_pair(s_seq, nullptr, c_seq, nullptr, 0, s_enc, c_enc);

    // ---- decoders (pair) ----
    vss_pair(c_enc, pc_seq, s_enc, ps_seq, 2, t1, t2);
    dn_pair_kernel<<<256, 256, 0, stream>>>(c_enc, t1, dn1_w, dn1_b,
                                            s_enc, t2, dn2_w, dn2_b,
                                            tgt, tgt_bf);

    // ---- FFN + tail ----
    GJob jf = Z;
    jf.A = tgt_bf; jf.W = wb_lin1; jf.bias = lin1_b; jf.Cb = ffn_bf;
    launch_gemm(&jf, 1, MROWS, 2048, 512, 1);
    GJob jg = Z;
    jg.A = ffn_bf; jg.W = wb_lin2; jg.bias = lin2_b; jg.Cf = ffnout;
    launch_gemm(&jg, 1, MROWS, 512, 2048, 0);
    ln2_kernel<<<256, 256, 0, stream>>>(tgt, ffnout, dn3_w, dn3_b,
                                        decn_w, decn_b, tgt3);
    from_seq_kernel<<<SEQ/256, 256, 0, stream>>>(tgt3, out);
}